// Round 3
// baseline (160.220 us; speedup 1.0000x reference)
//
#include <hip/hip_runtime.h>
#include <hip/hip_bf16.h>

// SpatialBranch: 1088 box-pair indicator maps -> conv1(2->64,5x5)+pool2 ->
// conv2(64->32,5x5)+pool2 -> spatial mean -> FC(32->512)+ReLU, plus slicing.
//
// Round 3 changes (phase-2 VALU addressing + residual LDS conflicts):
//  - h1 TRANSPOSED in LDS: 8 planes [slot][pos] of 8B, plane stride 8256 B.
//    A-reads become ds_read_b64 with compile-time immediate offsets (s-loop
//    fully unrolled) -> zero VALU in MFMA loop; reads/writes contiguous ->
//    conflict-free (2 lanes/bank). No swizzle at all.
//  - Inactive tiles branchless: vb points at zero pad rows (904..1028) ->
//    acc stays 0, bias-only c2 write stays correct.
//  - B-fragments stored PAIRED so one uint4 L2 load feeds 2 K-steps.
//  - fcw row prefetched to registers after MFMA loop (hides tail L2 latency).

#define NPAIRS 1088
#define FEAT_SZ (NPAIRS * 512)

typedef float f32x16 __attribute__((ext_vector_type(16)));

// workspace layout (bytes)
#define WS_V 0            // V[2][10][10][64] bf16 = 25600 (pair-independent conv1 window table)
#define WS_C2B 25600      // 32 f32 (conv1-bias folded through conv2)
#define WS_BFRAG 25728    // 100*64*8 fp8 = 51200, paired: [s/2][lane][2] uint2
// total 76928 bytes of ws

// LDS layout (bytes)
#define H1_PLANE 8256     // 1032 rows x 8B per slot-plane
#define H1_BYTES 66048    // 8 planes; rows 900..1031 stay zero (dummy-read pad)
                          // phase>=3: c2 [676][32] bf16 = 43264 (aliases h1)
#define SM_HM 66048       // h_mean [32] f32
#define SM_PART 66176     // partial [16][32] f32 = 2048
#define SMEM_BYTES 68224

__device__ __forceinline__ unsigned short f2bf(float f) {
  __hip_bfloat16 h = __float2bfloat16(f);
  unsigned short u;
  __builtin_memcpy(&u, &h, 2);
  return u;
}
__device__ __forceinline__ float bflo(unsigned int u) { return __uint_as_float(u << 16); }
__device__ __forceinline__ float bfhi(unsigned int u) { return __uint_as_float(u & 0xffff0000u); }

__device__ __forceinline__ void pair_ij(int k, int* pi, int* pj) {
  int i = 0, rem = k;
  while (rem >= 16 - i) { rem -= 16 - i; ++i; }
  *pi = i;
  *pj = i + 1 + rem;
}

// window state for coordinate z vs interval [a,b): 0 empty, 1..4 left-partial
// (k0=s,k1=5), 5 full, 6..9 right-partial (k0=0,k1=s-5). Valid since b-a>=4.
__device__ __forceinline__ int stz(int z, int a, int b) {
  if (z >= a) {
    if (z >= b) return 0;
    if (z <= b - 5) return 5;
    return 5 + (b - z);
  }
  if (z >= a - 4) return a - z;
  return 0;
}

__global__ void prep_kernel(const float* __restrict__ w1, const float* __restrict__ b1,
                            const float* __restrict__ w2, float* __restrict__ out,
                            unsigned char* __restrict__ ws) {
  int tid = blockIdx.x * blockDim.x + threadIdx.x;

  if (tid < 12800) {
    // V[c][sy][sx][o]: conv1 response of window-state (sy,sx) = rect subsum of w1[o][c]
    int o = tid & 63;
    int q = tid >> 6;
    int sx = q % 10; q /= 10;
    int sy = q % 10;
    int c = q / 10;
    int ky0 = (sy <= 4) ? sy : 0;
    int ky1 = (sy == 0) ? 0 : ((sy <= 5) ? 5 : sy - 5);
    int kx0 = (sx <= 4) ? sx : 0;
    int kx1 = (sx == 0) ? 0 : ((sx <= 5) ? 5 : sx - 5);
    const float* w = w1 + (o * 2 + c) * 25;
    float v = 0.f;
    for (int ky = ky0; ky < ky1; ++ky)
      for (int kx = kx0; kx < kx1; ++kx) v += w[ky * 5 + kx];
    ((unsigned short*)(ws + WS_V))[(c * 100 + sy * 10 + sx) * 64 + o] = f2bf(v);
  } else if (tid < 12832) {
    // C2B[oc] = sum_ic b1[ic] * sum_tap w2[oc][ic][tap]
    int oc = tid - 12800;
    float s = 0.f;
    for (int ic = 0; ic < 64; ++ic) {
      const float* wp = w2 + (oc * 64 + ic) * 25;
      float t = 0.f;
      for (int q2 = 0; q2 < 25; ++q2) t += wp[q2];
      s += b1[ic] * t;
    }
    ((float*)(ws + WS_C2B))[oc] = s;
  } else if (tid < 13920) {
    // slicing output (as float values; d_out read back as float32)
    int p = tid - 12832;
    int b = p / 136, k = p % 136, i, j;
    pair_ij(k, &i, &j);
    out[FEAT_SZ + p * 3 + 0] = (float)b;
    out[FEAT_SZ + p * 3 + 1] = (float)i;
    out[FEAT_SZ + p * 3 + 2] = (float)j;
  } else if (tid < 20320) {
    // conv2 B fragments (fp8): B[k][n], k=(lane>>5)*8+i within s-step, n=lane&31
    // K order: kk = tap*64 + ic ; s = tap*4 + icblock. PAIRED layout:
    // uint2 index = (s>>1)*128 + lane*2 + (s&1)  (one uint4 load = 2 K-steps)
    int idx = tid - 13920;
    int s = idx >> 6, lane = idx & 63;
    int tap = s >> 2, icb = (s & 3) * 16;
    int n = lane & 31, hi = lane >> 5;
    float v[8];
    for (int i2 = 0; i2 < 8; ++i2) {
      int ic = icb + hi * 8 + i2;
      v[i2] = w2[(n * 64 + ic) * 25 + tap];
    }
    unsigned q0 = 0, q1 = 0;
    q0 = __builtin_amdgcn_cvt_pk_fp8_f32(v[0], v[1], q0, false);
    q0 = __builtin_amdgcn_cvt_pk_fp8_f32(v[2], v[3], q0, true);
    q1 = __builtin_amdgcn_cvt_pk_fp8_f32(v[4], v[5], q1, false);
    q1 = __builtin_amdgcn_cvt_pk_fp8_f32(v[6], v[7], q1, true);
    ((uint2*)(ws + WS_BFRAG))[(s >> 1) * 128 + lane * 2 + (s & 1)] = make_uint2(q0, q1);
  }
}

__global__ __launch_bounds__(512, 4) void main_kernel(
    const float* __restrict__ bboxes, const float* __restrict__ b2,
    const float* __restrict__ fcw, const float* __restrict__ fcb,
    const unsigned char* __restrict__ ws, float* __restrict__ out) {
  __shared__ __align__(16) unsigned char smem[SMEM_BYTES];
  const int tid = threadIdx.x;
  const int lane = tid & 63;
  const int wid = tid >> 6;
  const int p = blockIdx.x;

  // ---- pair constants (uniform) ----
  int b = p / 136, k = p % 136, bi, bj;
  pair_ij(k, &bi, &bj);
  const float* bbA = bboxes + (b * 17 + bi) * 4;
  const float* bbB = bboxes + (b * 17 + bj) * 4;
  int ax[2], ay[2], bx[2], by[2];
  {
    auto cl = [](float v) { int t = (int)ceilf(v); return t < 0 ? 0 : (t > 64 ? 64 : t); };
    ax[0] = cl(bbA[0]); ay[0] = cl(bbA[1]); bx[0] = cl(bbA[2]); by[0] = cl(bbA[3]);
    ax[1] = cl(bbB[0]); ay[1] = cl(bbB[1]); bx[1] = cl(bbB[2]); by[1] = cl(bbB[3]);
  }

  // ---- phase 0: zero h1T (8 planes x 8256 B) ----
  for (int idx = tid; idx < (H1_BYTES >> 4); idx += 512)
    ((uint4*)smem)[idx] = make_uint4(0, 0, 0, 0);
  __syncthreads();

  // ---- phase 1: conv1 + pool1 via V lookups (L1/L2); h1 fp8 transposed, no b1 ----
  {
    const unsigned short* Vg = (const unsigned short*)(ws + WS_V);
    for (int pos = tid; pos < 900; pos += 512) {
      int py = pos / 30, px = pos - py * 30;
      int oy = py * 2, ox = px * 2;
      int sy[2][2], sx[2][2];
#pragma unroll
      for (int c = 0; c < 2; ++c) {
        sy[c][0] = stz(oy, ay[c], by[c]);
        sy[c][1] = stz(oy + 1, ay[c], by[c]);
        sx[c][0] = stz(ox, ax[c], bx[c]);
        sx[c][1] = stz(ox + 1, ax[c], bx[c]);
      }
      bool e0 = ((sy[0][0] | sy[0][1]) == 0) || ((sx[0][0] | sx[0][1]) == 0);
      bool e1 = ((sy[1][0] | sy[1][1]) == 0) || ((sx[1][0] | sx[1][1]) == 0);
      if (e0 && e1) continue;  // planes already zeroed at this pos

      const uint4* r0[4];
      const uint4* r1[4];
#pragma unroll
      for (int dy = 0; dy < 2; ++dy)
#pragma unroll
        for (int dx = 0; dx < 2; ++dx) {
          r0[dy * 2 + dx] = (const uint4*)(Vg + (0 * 100 + sy[0][dy] * 10 + sx[0][dx]) * 64);
          r1[dy * 2 + dx] = (const uint4*)(Vg + (1 * 100 + sy[1][dy] * 10 + sx[1][dx]) * 64);
        }

      unsigned hbase = (unsigned)pos * 8u;
#pragma unroll
      for (int g = 0; g < 8; ++g) {  // 8 channels per group -> plane g
        float mx[8];
#pragma unroll
        for (int sp = 0; sp < 4; ++sp) {
          uint4 u0 = r0[sp][g];
          uint4 u1 = r1[sp][g];
          unsigned a0[4] = {u0.x, u0.y, u0.z, u0.w};
          unsigned a1[4] = {u1.x, u1.y, u1.z, u1.w};
#pragma unroll
          for (int d = 0; d < 4; ++d) {
            float vl = bflo(a0[d]) + bflo(a1[d]);
            float vh = bfhi(a0[d]) + bfhi(a1[d]);
            if (sp == 0) { mx[2 * d] = vl; mx[2 * d + 1] = vh; }
            else { mx[2 * d] = fmaxf(mx[2 * d], vl); mx[2 * d + 1] = fmaxf(mx[2 * d + 1], vh); }
          }
        }
        unsigned q0 = 0, q1 = 0;
        q0 = __builtin_amdgcn_cvt_pk_fp8_f32(mx[0], mx[1], q0, false);
        q0 = __builtin_amdgcn_cvt_pk_fp8_f32(mx[2], mx[3], q0, true);
        q1 = __builtin_amdgcn_cvt_pk_fp8_f32(mx[4], mx[5], q1, false);
        q1 = __builtin_amdgcn_cvt_pk_fp8_f32(mx[6], mx[7], q1, true);
        *(uint2*)(smem + hbase + g * H1_PLANE) = make_uint2(q0, q1);  // imm offset
      }
    }
  }
  __syncthreads();

  // ---- phase 2: conv2 as fp8 MFMA implicit GEMM (zero-VALU inner loop) ----
  const int oc = lane & 31;
  const float c2bb = ((const float*)(ws + WS_C2B))[oc] + b2[oc];

  // active conv2 output row range (h1 zero outside support; bias folded -> valid skip)
  int s0a = ay[0] - 4 < 0 ? 0 : ay[0] - 4;
  int s0b = ay[1] - 4 < 0 ? 0 : ay[1] - 4;
  int pre0 = s0a < s0b ? s0a : s0b;
  int e0a = by[0] < 60 ? by[0] : 60;
  int e0b = by[1] < 60 ? by[1] : 60;
  int pre1 = e0a > e0b ? e0a : e0b;
  int pr0 = pre0 >> 1, pr1 = (pre1 - 1) >> 1;
  int or0 = pr0 - 4 < 0 ? 0 : pr0 - 4;
  int or1 = pr1 > 25 ? 25 : pr1;
  int poslo = or0 * 26, poshi = (or1 + 1) * 26;

  int tb[3]; bool act[3]; unsigned vb[3]; bool anyact = false;
  const unsigned hvo = (unsigned)(lane >> 5) * H1_PLANE;
#pragma unroll
  for (int ti = 0; ti < 3; ++ti) {
    int t = wid + ti * 8;
    tb[ti] = t * 32;
    bool a = (t < 22) && (tb[ti] < poshi) && (tb[ti] + 32 > poslo);
    act[ti] = a; anyact |= a;
    int pos = tb[ti] + (lane & 31);
    if (pos > 675) pos = 675;
    int oy2 = pos / 26, ox2 = pos - oy2 * 26;
    // inactive tiles read the zero pad rows (904..1028) -> acc stays 0
    vb[ti] = (a ? (unsigned)(oy2 * 30 + ox2) : 904u) * 8u + hvo;
  }

  f32x16 acc[3];
#pragma unroll
  for (int ti = 0; ti < 3; ++ti)
#pragma unroll
    for (int r = 0; r < 16; ++r) acc[ti][r] = 0.f;

  if (anyact) {
    const uint4* bfragp4 = (const uint4*)(ws + WS_BFRAG);
#pragma unroll
    for (int s2 = 0; s2 < 50; ++s2) {
      uint4 bq = bfragp4[s2 * 64 + lane];
      long long bop0 = __builtin_bit_cast(long long, make_uint2(bq.x, bq.y));
      long long bop1 = __builtin_bit_cast(long long, make_uint2(bq.z, bq.w));
      {
        const int s = 2 * s2;
        const int tap = s >> 2;
        const unsigned imm = (unsigned)((s & 3) * 2) * H1_PLANE + ((tap / 5) * 30 + tap % 5) * 8;
#pragma unroll
        for (int ti = 0; ti < 3; ++ti) {
          uint2 aq = *(const uint2*)(smem + vb[ti] + imm);
          acc[ti] = __builtin_amdgcn_mfma_f32_32x32x16_fp8_fp8(
              __builtin_bit_cast(long long, aq), bop0, acc[ti], 0, 0, 0);
        }
      }
      {
        const int s = 2 * s2 + 1;
        const int tap = s >> 2;
        const unsigned imm = (unsigned)((s & 3) * 2) * H1_PLANE + ((tap / 5) * 30 + tap % 5) * 8;
#pragma unroll
        for (int ti = 0; ti < 3; ++ti) {
          uint2 aq = *(const uint2*)(smem + vb[ti] + imm);
          acc[ti] = __builtin_amdgcn_mfma_f32_32x32x16_fp8_fp8(
              __builtin_bit_cast(long long, aq), bop1, acc[ti], 0, 0, 0);
        }
      }
    }
  }

  // prefetch FC row into registers; loads drain during the barrier / phase 3
  float4 wreg[8];
  {
    const float4* wrow4 = (const float4*)(fcw + tid * 32);
#pragma unroll
    for (int q = 0; q < 8; ++q) wreg[q] = wrow4[q];
  }
  const float fcbr = fcb[tid];

  __syncthreads();  // all h1 reads done; c2 may now overwrite h1's LDS region

  // every tile writes (inactive tiles have acc==0 -> bias value), covering all 676
  unsigned short* c2 = (unsigned short*)smem;
#pragma unroll
  for (int ti = 0; ti < 3; ++ti) {
#pragma unroll
    for (int r = 0; r < 16; ++r) {
      int row = (r & 3) + 8 * (r >> 2) + 4 * (lane >> 5);
      int pos = tb[ti] + row;
      if (pos < 676) c2[pos * 32 + oc] = f2bf(acc[ti][r] + c2bb);
    }
  }
  __syncthreads();

  // ---- phase 3: pool2 + spatial mean (lanes 0..31 -> consecutive oc) ----
  {
    float* partial = (float*)(smem + SM_PART);
    int moc = lane & 31;
    int mi = wid * 2 + (lane >> 5);  // 0..15
    float ssum = 0.f;
    for (int q = mi; q < 169; q += 16) {
      int py = q / 13, px = q - py * 13;
      int p0 = (py * 2) * 26 + px * 2;
      float v00 = bflo(c2[p0 * 32 + moc]);
      float v01 = bflo(c2[(p0 + 1) * 32 + moc]);
      float v10 = bflo(c2[(p0 + 26) * 32 + moc]);
      float v11 = bflo(c2[(p0 + 27) * 32 + moc]);
      ssum += fmaxf(fmaxf(v00, v01), fmaxf(v10, v11));
    }
    partial[mi * 32 + moc] = ssum;
  }
  __syncthreads();
  if (tid < 32) {
    const float* partial = (const float*)(smem + SM_PART);
    float s = 0.f;
#pragma unroll
    for (int mi = 0; mi < 16; ++mi) s += partial[mi * 32 + tid];
    ((float*)(smem + SM_HM))[tid] = s * (1.0f / 169.0f);
  }
  __syncthreads();

  // ---- phase 4: FC + ReLU (weights already in registers) ----
  {
    const float* hm = (const float*)(smem + SM_HM);
    float a = fcbr;
#pragma unroll
    for (int q = 0; q < 8; ++q) {
      a = fmaf(hm[q * 4 + 0], wreg[q].x, a);
      a = fmaf(hm[q * 4 + 1], wreg[q].y, a);
      a = fmaf(hm[q * 4 + 2], wreg[q].z, a);
      a = fmaf(hm[q * 4 + 3], wreg[q].w, a);
    }
    out[p * 512 + tid] = fmaxf(a, 0.f);
  }
}

extern "C" void kernel_launch(void* const* d_in, const int* in_sizes, int n_in,
                              void* d_out, int out_size, void* d_ws, size_t ws_size,
                              hipStream_t stream) {
  const float* bboxes = (const float*)d_in[0];
  const float* w1 = (const float*)d_in[1];
  const float* b1 = (const float*)d_in[2];
  const float* w2 = (const float*)d_in[3];
  const float* b2 = (const float*)d_in[4];
  const float* fcw = (const float*)d_in[5];
  const float* fcb = (const float*)d_in[6];
  float* out = (float*)d_out;
  unsigned char* ws = (unsigned char*)d_ws;

  hipLaunchKernelGGL(prep_kernel, dim3(80), dim3(256), 0, stream, w1, b1, w2, out, ws);
  hipLaunchKernelGGL(main_kernel, dim3(NPAIRS), dim3(512), 0, stream, bboxes, b2, fcw, fcb, ws, out);
}

// Round 4
// 106.981 us; speedup vs baseline: 1.4976x; 1.4976x over previous
//
#include <hip/hip_runtime.h>
#include <hip/hip_bf16.h>

// SpatialBranch: 1088 box-pair indicator maps -> conv1(2->64,5x5)+pool2 ->
// conv2(64->32,5x5)+pool2 -> spatial mean -> FC(32->512)+ReLU, plus slicing.
//
// Round 4 changes:
//  - REVERT fcw register prefetch (R3 post-mortem: it spilled 128 B/thread to
//    scratch -> 72 MB of HBM writes; phase 4 now loads fcw from L2 directly).
//  - Compact tile assignment: t = t_first + wid + ti*8 over the ACTIVE tile
//    range only; out-of-range tiles get a bias-only write (h1 is zero there,
//    bias folded -> exact). Cuts issued ds_read+MFMA ~35-50%.
//  - Keeps R3 wins: transposed h1 planes (conflict-free, imm-offset ds_read),
//    paired B-fragments, fp8 MFMA, 68.6 KB LDS -> 2 blocks/CU.

#define NPAIRS 1088
#define FEAT_SZ (NPAIRS * 512)

typedef float f32x16 __attribute__((ext_vector_type(16)));

// workspace layout (bytes)
#define WS_V 0            // V[2][10][10][64] bf16 = 25600 (pair-independent conv1 window table)
#define WS_C2B 25600      // 32 f32 (conv1-bias folded through conv2)
#define WS_BFRAG 25728    // 100*64*8 fp8 = 51200, paired: [s/2][lane][2] uint2
// total 76928 bytes of ws

// LDS layout (bytes)
#define H1_PLANE 8256     // 1032 rows x 8B per slot-plane
#define H1_BYTES 66048    // 8 planes; rows 900..1031 stay zero (dummy-read pad)
                          // phase>=3: c2 [676][32] bf16 = 43264 (aliases h1)
#define SM_HM 66048       // h_mean [32] f32
#define SM_PART 66176     // partial [16][32] f32 = 2048
#define SMEM_BYTES 68224

__device__ __forceinline__ unsigned short f2bf(float f) {
  __hip_bfloat16 h = __float2bfloat16(f);
  unsigned short u;
  __builtin_memcpy(&u, &h, 2);
  return u;
}
__device__ __forceinline__ float bflo(unsigned int u) { return __uint_as_float(u << 16); }
__device__ __forceinline__ float bfhi(unsigned int u) { return __uint_as_float(u & 0xffff0000u); }

__device__ __forceinline__ void pair_ij(int k, int* pi, int* pj) {
  int i = 0, rem = k;
  while (rem >= 16 - i) { rem -= 16 - i; ++i; }
  *pi = i;
  *pj = i + 1 + rem;
}

// window state for coordinate z vs interval [a,b): 0 empty, 1..4 left-partial
// (k0=s,k1=5), 5 full, 6..9 right-partial (k0=0,k1=s-5). Valid since b-a>=4.
__device__ __forceinline__ int stz(int z, int a, int b) {
  if (z >= a) {
    if (z >= b) return 0;
    if (z <= b - 5) return 5;
    return 5 + (b - z);
  }
  if (z >= a - 4) return a - z;
  return 0;
}

__global__ void prep_kernel(const float* __restrict__ w1, const float* __restrict__ b1,
                            const float* __restrict__ w2, float* __restrict__ out,
                            unsigned char* __restrict__ ws) {
  int tid = blockIdx.x * blockDim.x + threadIdx.x;

  if (tid < 12800) {
    // V[c][sy][sx][o]: conv1 response of window-state (sy,sx) = rect subsum of w1[o][c]
    int o = tid & 63;
    int q = tid >> 6;
    int sx = q % 10; q /= 10;
    int sy = q % 10;
    int c = q / 10;
    int ky0 = (sy <= 4) ? sy : 0;
    int ky1 = (sy == 0) ? 0 : ((sy <= 5) ? 5 : sy - 5);
    int kx0 = (sx <= 4) ? sx : 0;
    int kx1 = (sx == 0) ? 0 : ((sx <= 5) ? 5 : sx - 5);
    const float* w = w1 + (o * 2 + c) * 25;
    float v = 0.f;
    for (int ky = ky0; ky < ky1; ++ky)
      for (int kx = kx0; kx < kx1; ++kx) v += w[ky * 5 + kx];
    ((unsigned short*)(ws + WS_V))[(c * 100 + sy * 10 + sx) * 64 + o] = f2bf(v);
  } else if (tid < 12832) {
    // C2B[oc] = sum_ic b1[ic] * sum_tap w2[oc][ic][tap]
    int oc = tid - 12800;
    float s = 0.f;
    for (int ic = 0; ic < 64; ++ic) {
      const float* wp = w2 + (oc * 64 + ic) * 25;
      float t = 0.f;
      for (int q2 = 0; q2 < 25; ++q2) t += wp[q2];
      s += b1[ic] * t;
    }
    ((float*)(ws + WS_C2B))[oc] = s;
  } else if (tid < 13920) {
    // slicing output (as float values; d_out read back as float32)
    int p = tid - 12832;
    int b = p / 136, k = p % 136, i, j;
    pair_ij(k, &i, &j);
    out[FEAT_SZ + p * 3 + 0] = (float)b;
    out[FEAT_SZ + p * 3 + 1] = (float)i;
    out[FEAT_SZ + p * 3 + 2] = (float)j;
  } else if (tid < 20320) {
    // conv2 B fragments (fp8): B[k][n], k=(lane>>5)*8+i within s-step, n=lane&31
    // K order: kk = tap*64 + ic ; s = tap*4 + icblock. PAIRED layout:
    // uint2 index = (s>>1)*128 + lane*2 + (s&1)  (one uint4 load = 2 K-steps)
    int idx = tid - 13920;
    int s = idx >> 6, lane = idx & 63;
    int tap = s >> 2, icb = (s & 3) * 16;
    int n = lane & 31, hi = lane >> 5;
    float v[8];
    for (int i2 = 0; i2 < 8; ++i2) {
      int ic = icb + hi * 8 + i2;
      v[i2] = w2[(n * 64 + ic) * 25 + tap];
    }
    unsigned q0 = 0, q1 = 0;
    q0 = __builtin_amdgcn_cvt_pk_fp8_f32(v[0], v[1], q0, false);
    q0 = __builtin_amdgcn_cvt_pk_fp8_f32(v[2], v[3], q0, true);
    q1 = __builtin_amdgcn_cvt_pk_fp8_f32(v[4], v[5], q1, false);
    q1 = __builtin_amdgcn_cvt_pk_fp8_f32(v[6], v[7], q1, true);
    ((uint2*)(ws + WS_BFRAG))[(s >> 1) * 128 + lane * 2 + (s & 1)] = make_uint2(q0, q1);
  }
}

__global__ __launch_bounds__(512, 4) void main_kernel(
    const float* __restrict__ bboxes, const float* __restrict__ b2,
    const float* __restrict__ fcw, const float* __restrict__ fcb,
    const unsigned char* __restrict__ ws, float* __restrict__ out) {
  __shared__ __align__(16) unsigned char smem[SMEM_BYTES];
  const int tid = threadIdx.x;
  const int lane = tid & 63;
  const int wid = tid >> 6;
  const int p = blockIdx.x;

  // ---- pair constants (uniform) ----
  int b = p / 136, k = p % 136, bi, bj;
  pair_ij(k, &bi, &bj);
  const float* bbA = bboxes + (b * 17 + bi) * 4;
  const float* bbB = bboxes + (b * 17 + bj) * 4;
  int ax[2], ay[2], bx[2], by[2];
  {
    auto cl = [](float v) { int t = (int)ceilf(v); return t < 0 ? 0 : (t > 64 ? 64 : t); };
    ax[0] = cl(bbA[0]); ay[0] = cl(bbA[1]); bx[0] = cl(bbA[2]); by[0] = cl(bbA[3]);
    ax[1] = cl(bbB[0]); ay[1] = cl(bbB[1]); bx[1] = cl(bbB[2]); by[1] = cl(bbB[3]);
  }

  // ---- phase 0: zero h1T (8 planes x 8256 B) ----
  for (int idx = tid; idx < (H1_BYTES >> 4); idx += 512)
    ((uint4*)smem)[idx] = make_uint4(0, 0, 0, 0);
  __syncthreads();

  // ---- phase 1: conv1 + pool1 via V lookups (L1/L2); h1 fp8 transposed, no b1 ----
  {
    const unsigned short* Vg = (const unsigned short*)(ws + WS_V);
    for (int pos = tid; pos < 900; pos += 512) {
      int py = pos / 30, px = pos - py * 30;
      int oy = py * 2, ox = px * 2;
      int sy[2][2], sx[2][2];
#pragma unroll
      for (int c = 0; c < 2; ++c) {
        sy[c][0] = stz(oy, ay[c], by[c]);
        sy[c][1] = stz(oy + 1, ay[c], by[c]);
        sx[c][0] = stz(ox, ax[c], bx[c]);
        sx[c][1] = stz(ox + 1, ax[c], bx[c]);
      }
      bool e0 = ((sy[0][0] | sy[0][1]) == 0) || ((sx[0][0] | sx[0][1]) == 0);
      bool e1 = ((sy[1][0] | sy[1][1]) == 0) || ((sx[1][0] | sx[1][1]) == 0);
      if (e0 && e1) continue;  // planes already zeroed at this pos

      const uint4* r0[4];
      const uint4* r1[4];
#pragma unroll
      for (int dy = 0; dy < 2; ++dy)
#pragma unroll
        for (int dx = 0; dx < 2; ++dx) {
          r0[dy * 2 + dx] = (const uint4*)(Vg + (0 * 100 + sy[0][dy] * 10 + sx[0][dx]) * 64);
          r1[dy * 2 + dx] = (const uint4*)(Vg + (1 * 100 + sy[1][dy] * 10 + sx[1][dx]) * 64);
        }

      unsigned hbase = (unsigned)pos * 8u;
#pragma unroll
      for (int g = 0; g < 8; ++g) {  // 8 channels per group -> plane g
        float mx[8];
#pragma unroll
        for (int sp = 0; sp < 4; ++sp) {
          uint4 u0 = r0[sp][g];
          uint4 u1 = r1[sp][g];
          unsigned a0[4] = {u0.x, u0.y, u0.z, u0.w};
          unsigned a1[4] = {u1.x, u1.y, u1.z, u1.w};
#pragma unroll
          for (int d = 0; d < 4; ++d) {
            float vl = bflo(a0[d]) + bflo(a1[d]);
            float vh = bfhi(a0[d]) + bfhi(a1[d]);
            if (sp == 0) { mx[2 * d] = vl; mx[2 * d + 1] = vh; }
            else { mx[2 * d] = fmaxf(mx[2 * d], vl); mx[2 * d + 1] = fmaxf(mx[2 * d + 1], vh); }
          }
        }
        unsigned q0 = 0, q1 = 0;
        q0 = __builtin_amdgcn_cvt_pk_fp8_f32(mx[0], mx[1], q0, false);
        q0 = __builtin_amdgcn_cvt_pk_fp8_f32(mx[2], mx[3], q0, true);
        q1 = __builtin_amdgcn_cvt_pk_fp8_f32(mx[4], mx[5], q1, false);
        q1 = __builtin_amdgcn_cvt_pk_fp8_f32(mx[6], mx[7], q1, true);
        *(uint2*)(smem + hbase + g * H1_PLANE) = make_uint2(q0, q1);  // imm offset
      }
    }
  }
  __syncthreads();

  // ---- phase 2: conv2 as fp8 MFMA implicit GEMM over ACTIVE tiles only ----
  const int oc = lane & 31;
  const float c2bb = ((const float*)(ws + WS_C2B))[oc] + b2[oc];

  // active conv2 output row range (h1 zero outside support; bias folded -> valid skip)
  int s0a = ay[0] - 4 < 0 ? 0 : ay[0] - 4;
  int s0b = ay[1] - 4 < 0 ? 0 : ay[1] - 4;
  int pre0 = s0a < s0b ? s0a : s0b;
  int e0a = by[0] < 60 ? by[0] : 60;
  int e0b = by[1] < 60 ? by[1] : 60;
  int pre1 = e0a > e0b ? e0a : e0b;
  int pr0 = pre0 >> 1, pr1 = (pre1 - 1) >> 1;
  int or0 = pr0 - 4 < 0 ? 0 : pr0 - 4;
  int or1 = pr1 > 25 ? 25 : pr1;
  int poslo = or0 * 26, poshi = (or1 + 1) * 26;
  int t_first = poslo >> 5;
  int t_last = (poshi - 1) >> 5;  // <= 21

  // compact assignment over active tiles: t = t_first + wid + ti*8
  int tb[3]; int acts[3]; unsigned vb[3]; bool anyact = false;
  const unsigned hvo = (unsigned)(lane >> 5) * H1_PLANE;
#pragma unroll
  for (int ti = 0; ti < 3; ++ti) {
    int t = t_first + wid + ti * 8;
    bool a = (t <= t_last);
    acts[ti] = __builtin_amdgcn_readfirstlane(a ? 1 : 0);  // wave-uniform -> SGPR
    anyact |= a;
    tb[ti] = t * 32;
    int pos = tb[ti] + (lane & 31);
    if (pos > 675) pos = 675;
    int oy2 = pos / 26, ox2 = pos - oy2 * 26;
    vb[ti] = (a ? (unsigned)(oy2 * 30 + ox2) : 904u) * 8u + hvo;
  }

  f32x16 acc[3];
#pragma unroll
  for (int ti = 0; ti < 3; ++ti)
#pragma unroll
    for (int r = 0; r < 16; ++r) acc[ti][r] = 0.f;

  if (anyact) {
    const uint4* bfragp4 = (const uint4*)(ws + WS_BFRAG);
#pragma unroll
    for (int s2 = 0; s2 < 50; ++s2) {
      uint4 bq = bfragp4[s2 * 64 + lane];
      long long bop0 = __builtin_bit_cast(long long, make_uint2(bq.x, bq.y));
      long long bop1 = __builtin_bit_cast(long long, make_uint2(bq.z, bq.w));
      {
        const int s = 2 * s2;
        const int tap = s >> 2;
        const unsigned imm = (unsigned)((s & 3) * 2) * H1_PLANE + ((tap / 5) * 30 + tap % 5) * 8;
#pragma unroll
        for (int ti = 0; ti < 3; ++ti) {
          if (!acts[ti]) continue;
          uint2 aq = *(const uint2*)(smem + vb[ti] + imm);
          acc[ti] = __builtin_amdgcn_mfma_f32_32x32x16_fp8_fp8(
              __builtin_bit_cast(long long, aq), bop0, acc[ti], 0, 0, 0);
        }
      }
      {
        const int s = 2 * s2 + 1;
        const int tap = s >> 2;
        const unsigned imm = (unsigned)((s & 3) * 2) * H1_PLANE + ((tap / 5) * 30 + tap % 5) * 8;
#pragma unroll
        for (int ti = 0; ti < 3; ++ti) {
          if (!acts[ti]) continue;
          uint2 aq = *(const uint2*)(smem + vb[ti] + imm);
          acc[ti] = __builtin_amdgcn_mfma_f32_32x32x16_fp8_fp8(
              __builtin_bit_cast(long long, aq), bop1, acc[ti], 0, 0, 0);
        }
      }
    }
  }
  __syncthreads();  // all h1 reads done; c2 may now overwrite h1's LDS region

  // c2 writes: compact owners write computed tiles; fixed mapping covers the
  // rest with bias only (exact: h1 is zero outside [t_first,t_last] range).
  unsigned short* c2 = (unsigned short*)smem;
#pragma unroll
  for (int ti = 0; ti < 3; ++ti) {
    if (!acts[ti]) continue;
#pragma unroll
    for (int r = 0; r < 16; ++r) {
      int row = (r & 3) + 8 * (r >> 2) + 4 * (lane >> 5);
      int pos = tb[ti] + row;
      if (pos < 676) c2[pos * 32 + oc] = f2bf(acc[ti][r] + c2bb);
    }
  }
  {
    unsigned short cu = f2bf(c2bb);
#pragma unroll
    for (int ti = 0; ti < 3; ++ti) {
      int tf = wid + ti * 8;
      if (tf < 22 && (tf < t_first || tf > t_last)) {
#pragma unroll
        for (int r = 0; r < 16; ++r) {
          int row = (r & 3) + 8 * (r >> 2) + 4 * (lane >> 5);
          int pos = tf * 32 + row;
          if (pos < 676) c2[pos * 32 + oc] = cu;
        }
      }
    }
  }
  __syncthreads();

  // ---- phase 3: pool2 + spatial mean (lanes 0..31 -> consecutive oc) ----
  {
    float* partial = (float*)(smem + SM_PART);
    int moc = lane & 31;
    int mi = wid * 2 + (lane >> 5);  // 0..15
    float ssum = 0.f;
    for (int q = mi; q < 169; q += 16) {
      int py = q / 13, px = q - py * 13;
      int p0 = (py * 2) * 26 + px * 2;
      float v00 = bflo(c2[p0 * 32 + moc]);
      float v01 = bflo(c2[(p0 + 1) * 32 + moc]);
      float v10 = bflo(c2[(p0 + 26) * 32 + moc]);
      float v11 = bflo(c2[(p0 + 27) * 32 + moc]);
      ssum += fmaxf(fmaxf(v00, v01), fmaxf(v10, v11));
    }
    partial[mi * 32 + moc] = ssum;
  }
  __syncthreads();
  if (tid < 32) {
    const float* partial = (const float*)(smem + SM_PART);
    float s = 0.f;
#pragma unroll
    for (int mi = 0; mi < 16; ++mi) s += partial[mi * 32 + tid];
    ((float*)(smem + SM_HM))[tid] = s * (1.0f / 169.0f);
  }
  __syncthreads();

  // ---- phase 4: FC + ReLU (fcw streamed from L2; no register prefetch) ----
  {
    const float* hm = (const float*)(smem + SM_HM);
    float a = fcb[tid];
    const float* wrow = fcw + tid * 32;
#pragma unroll 8
    for (int o2 = 0; o2 < 32; ++o2) a = fmaf(hm[o2], wrow[o2], a);
    out[p * 512 + tid] = fmaxf(a, 0.f);
  }
}

extern "C" void kernel_launch(void* const* d_in, const int* in_sizes, int n_in,
                              void* d_out, int out_size, void* d_ws, size_t ws_size,
                              hipStream_t stream) {
  const float* bboxes = (const float*)d_in[0];
  const float* w1 = (const float*)d_in[1];
  const float* b1 = (const float*)d_in[2];
  const float* w2 = (const float*)d_in[3];
  const float* b2 = (const float*)d_in[4];
  const float* fcw = (const float*)d_in[5];
  const float* fcb = (const float*)d_in[6];
  float* out = (float*)d_out;
  unsigned char* ws = (unsigned char*)d_ws;

  hipLaunchKernelGGL(prep_kernel, dim3(80), dim3(256), 0, stream, w1, b1, w2, out, ws);
  hipLaunchKernelGGL(main_kernel, dim3(NPAIRS), dim3(512), 0, stream, bboxes, b2, fcw, fcb, ws, out);
}

// Round 5
// 80.804 us; speedup vs baseline: 1.9828x; 1.3240x over previous
//
#include <hip/hip_runtime.h>
#include <hip/hip_bf16.h>

// SpatialBranch: 1088 box-pair indicator maps -> conv1(2->64,5x5)+pool2 ->
// conv2(64->32,5x5)+pool2 -> spatial mean -> FC(32->512)+ReLU, plus slicing.
//
// Round 5 changes:
//  - conv2 via MX-scaled mfma_scale_f32_32x32x64_f8f6f4 (unit E8M0 scales):
//    2.14x fp8 MFMA rate, 4x fewer MFMA instrs (25 taps x K=64). A-operand =
//    4x ds_read_b64 from planes 4h..4h+3 (same conflict-free pattern, imm offs).
//  - Explicit 1-deep register prefetch of B-fragments (2x uint4 per tap).
//  - Phase 0 merged into phase 1 (empty positions write zeros) -> one less
//    barrier, ~25% less LDS write traffic. Planes shrunk to exactly 900 rows.

#define NPAIRS 1088
#define FEAT_SZ (NPAIRS * 512)

typedef float f32x16 __attribute__((ext_vector_type(16)));
typedef int v8i __attribute__((ext_vector_type(8)));

// workspace layout (bytes)
#define WS_V 0            // V[2][10][10][64] bf16 = 25600 (pair-independent conv1 window table)
#define WS_C2B 25600      // 32 f32 (conv1-bias folded through conv2)
#define WS_BFRAG 25728    // 25 taps x 64 lanes x 32B fp8 = 51200
// total 76928 bytes of ws

// LDS layout (bytes)
#define H1_PLANE 7200     // 900 rows x 8B per 8-channel plane
#define H1_BYTES 57600    // 8 planes; phase>=3: c2 [676][32] bf16 = 43264 aliases
#define SM_HM 57600       // h_mean [32] f32
#define SM_PART 57728     // partial [16][32] f32 = 2048
#define SMEM_BYTES 59776

__device__ __forceinline__ unsigned short f2bf(float f) {
  __hip_bfloat16 h = __float2bfloat16(f);
  unsigned short u;
  __builtin_memcpy(&u, &h, 2);
  return u;
}
__device__ __forceinline__ float bflo(unsigned int u) { return __uint_as_float(u << 16); }
__device__ __forceinline__ float bfhi(unsigned int u) { return __uint_as_float(u & 0xffff0000u); }

__device__ __forceinline__ void pair_ij(int k, int* pi, int* pj) {
  int i = 0, rem = k;
  while (rem >= 16 - i) { rem -= 16 - i; ++i; }
  *pi = i;
  *pj = i + 1 + rem;
}

// window state for coordinate z vs interval [a,b): 0 empty, 1..4 left-partial
// (k0=s,k1=5), 5 full, 6..9 right-partial (k0=0,k1=s-5). Valid since b-a>=4.
__device__ __forceinline__ int stz(int z, int a, int b) {
  if (z >= a) {
    if (z >= b) return 0;
    if (z <= b - 5) return 5;
    return 5 + (b - z);
  }
  if (z >= a - 4) return a - z;
  return 0;
}

__global__ void prep_kernel(const float* __restrict__ w1, const float* __restrict__ b1,
                            const float* __restrict__ w2, float* __restrict__ out,
                            unsigned char* __restrict__ ws) {
  int tid = blockIdx.x * blockDim.x + threadIdx.x;

  if (tid < 12800) {
    // V[c][sy][sx][o]: conv1 response of window-state (sy,sx) = rect subsum of w1[o][c]
    int o = tid & 63;
    int q = tid >> 6;
    int sx = q % 10; q /= 10;
    int sy = q % 10;
    int c = q / 10;
    int ky0 = (sy <= 4) ? sy : 0;
    int ky1 = (sy == 0) ? 0 : ((sy <= 5) ? 5 : sy - 5);
    int kx0 = (sx <= 4) ? sx : 0;
    int kx1 = (sx == 0) ? 0 : ((sx <= 5) ? 5 : sx - 5);
    const float* w = w1 + (o * 2 + c) * 25;
    float v = 0.f;
    for (int ky = ky0; ky < ky1; ++ky)
      for (int kx = kx0; kx < kx1; ++kx) v += w[ky * 5 + kx];
    ((unsigned short*)(ws + WS_V))[(c * 100 + sy * 10 + sx) * 64 + o] = f2bf(v);
  } else if (tid < 12832) {
    // C2B[oc] = sum_ic b1[ic] * sum_tap w2[oc][ic][tap]
    int oc = tid - 12800;
    float s = 0.f;
    for (int ic = 0; ic < 64; ++ic) {
      const float* wp = w2 + (oc * 64 + ic) * 25;
      float t = 0.f;
      for (int q2 = 0; q2 < 25; ++q2) t += wp[q2];
      s += b1[ic] * t;
    }
    ((float*)(ws + WS_C2B))[oc] = s;
  } else if (tid < 13920) {
    // slicing output (as float values; d_out read back as float32)
    int p = tid - 12832;
    int b = p / 136, k = p % 136, i, j;
    pair_ij(k, &i, &j);
    out[FEAT_SZ + p * 3 + 0] = (float)b;
    out[FEAT_SZ + p * 3 + 1] = (float)i;
    out[FEAT_SZ + p * 3 + 2] = (float)j;
  } else if (tid < 15520) {
    // conv2 B fragments (fp8) for K=64 MX MFMA: one tap per step.
    // lane l: n = l&31 (oc), h = l>>5; k-bytes = w2[oc][ic = h*32 + 0..31][tap]
    // layout: uint4 pair at [tap*128 + lane*2 + {0,1}] (32B per (tap,lane))
    int idx = tid - 13920;
    int tap = idx >> 6, lane = idx & 63;
    int n = lane & 31, h = lane >> 5;
    unsigned qd[8];
#pragma unroll
    for (int d = 0; d < 8; ++d) {
      float v0 = w2[(n * 64 + h * 32 + 4 * d + 0) * 25 + tap];
      float v1 = w2[(n * 64 + h * 32 + 4 * d + 1) * 25 + tap];
      float v2 = w2[(n * 64 + h * 32 + 4 * d + 2) * 25 + tap];
      float v3 = w2[(n * 64 + h * 32 + 4 * d + 3) * 25 + tap];
      unsigned q = 0;
      q = __builtin_amdgcn_cvt_pk_fp8_f32(v0, v1, q, false);
      q = __builtin_amdgcn_cvt_pk_fp8_f32(v2, v3, q, true);
      qd[d] = q;
    }
    uint4* Bp = (uint4*)(ws + WS_BFRAG);
    Bp[tap * 128 + lane * 2 + 0] = make_uint4(qd[0], qd[1], qd[2], qd[3]);
    Bp[tap * 128 + lane * 2 + 1] = make_uint4(qd[4], qd[5], qd[6], qd[7]);
  }
}

__global__ __launch_bounds__(512, 4) void main_kernel(
    const float* __restrict__ bboxes, const float* __restrict__ b2,
    const float* __restrict__ fcw, const float* __restrict__ fcb,
    const unsigned char* __restrict__ ws, float* __restrict__ out) {
  __shared__ __align__(16) unsigned char smem[SMEM_BYTES];
  const int tid = threadIdx.x;
  const int lane = tid & 63;
  const int wid = tid >> 6;
  const int p = blockIdx.x;

  // ---- pair constants (uniform) ----
  int b = p / 136, k = p % 136, bi, bj;
  pair_ij(k, &bi, &bj);
  const float* bbA = bboxes + (b * 17 + bi) * 4;
  const float* bbB = bboxes + (b * 17 + bj) * 4;
  int ax[2], ay[2], bx[2], by[2];
  {
    auto cl = [](float v) { int t = (int)ceilf(v); return t < 0 ? 0 : (t > 64 ? 64 : t); };
    ax[0] = cl(bbA[0]); ay[0] = cl(bbA[1]); bx[0] = cl(bbA[2]); by[0] = cl(bbA[3]);
    ax[1] = cl(bbB[0]); ay[1] = cl(bbB[1]); bx[1] = cl(bbB[2]); by[1] = cl(bbB[3]);
  }

  // ---- phase 1: conv1 + pool1 via V lookups; h1 fp8 transposed planes, no b1.
  //      Empty positions write zeros directly (no separate zeroing pass). ----
  {
    const unsigned short* Vg = (const unsigned short*)(ws + WS_V);
    for (int pos = tid; pos < 900; pos += 512) {
      int py = pos / 30, px = pos - py * 30;
      int oy = py * 2, ox = px * 2;
      int sy[2][2], sx[2][2];
#pragma unroll
      for (int c = 0; c < 2; ++c) {
        sy[c][0] = stz(oy, ay[c], by[c]);
        sy[c][1] = stz(oy + 1, ay[c], by[c]);
        sx[c][0] = stz(ox, ax[c], bx[c]);
        sx[c][1] = stz(ox + 1, ax[c], bx[c]);
      }
      bool e0 = ((sy[0][0] | sy[0][1]) == 0) || ((sx[0][0] | sx[0][1]) == 0);
      bool e1 = ((sy[1][0] | sy[1][1]) == 0) || ((sx[1][0] | sx[1][1]) == 0);
      unsigned hbase = (unsigned)pos * 8u;
      if (e0 && e1) {
#pragma unroll
        for (int g = 0; g < 8; ++g)
          *(uint2*)(smem + hbase + g * H1_PLANE) = make_uint2(0u, 0u);
        continue;
      }

      const uint4* r0[4];
      const uint4* r1[4];
#pragma unroll
      for (int dy = 0; dy < 2; ++dy)
#pragma unroll
        for (int dx = 0; dx < 2; ++dx) {
          r0[dy * 2 + dx] = (const uint4*)(Vg + (0 * 100 + sy[0][dy] * 10 + sx[0][dx]) * 64);
          r1[dy * 2 + dx] = (const uint4*)(Vg + (1 * 100 + sy[1][dy] * 10 + sx[1][dx]) * 64);
        }

#pragma unroll
      for (int g = 0; g < 8; ++g) {  // 8 channels per group -> plane g
        float mx[8];
#pragma unroll
        for (int sp = 0; sp < 4; ++sp) {
          uint4 u0 = r0[sp][g];
          uint4 u1 = r1[sp][g];
          unsigned a0[4] = {u0.x, u0.y, u0.z, u0.w};
          unsigned a1[4] = {u1.x, u1.y, u1.z, u1.w};
#pragma unroll
          for (int d = 0; d < 4; ++d) {
            float vl = bflo(a0[d]) + bflo(a1[d]);
            float vh = bfhi(a0[d]) + bfhi(a1[d]);
            if (sp == 0) { mx[2 * d] = vl; mx[2 * d + 1] = vh; }
            else { mx[2 * d] = fmaxf(mx[2 * d], vl); mx[2 * d + 1] = fmaxf(mx[2 * d + 1], vh); }
          }
        }
        unsigned q0 = 0, q1 = 0;
        q0 = __builtin_amdgcn_cvt_pk_fp8_f32(mx[0], mx[1], q0, false);
        q0 = __builtin_amdgcn_cvt_pk_fp8_f32(mx[2], mx[3], q0, true);
        q1 = __builtin_amdgcn_cvt_pk_fp8_f32(mx[4], mx[5], q1, false);
        q1 = __builtin_amdgcn_cvt_pk_fp8_f32(mx[6], mx[7], q1, true);
        *(uint2*)(smem + hbase + g * H1_PLANE) = make_uint2(q0, q1);
      }
    }
  }
  __syncthreads();

  // ---- phase 2: conv2 as K=64 MX fp8 MFMA implicit GEMM over ACTIVE tiles ----
  const int oc = lane & 31;
  const float c2bb = ((const float*)(ws + WS_C2B))[oc] + b2[oc];

  // active conv2 output row range (h1 zero outside support; bias folded -> valid skip)
  int s0a = ay[0] - 4 < 0 ? 0 : ay[0] - 4;
  int s0b = ay[1] - 4 < 0 ? 0 : ay[1] - 4;
  int pre0 = s0a < s0b ? s0a : s0b;
  int e0a = by[0] < 60 ? by[0] : 60;
  int e0b = by[1] < 60 ? by[1] : 60;
  int pre1 = e0a > e0b ? e0a : e0b;
  int pr0 = pre0 >> 1, pr1 = (pre1 - 1) >> 1;
  int or0 = pr0 - 4 < 0 ? 0 : pr0 - 4;
  int or1 = pr1 > 25 ? 25 : pr1;
  int poslo = or0 * 26, poshi = (or1 + 1) * 26;
  int t_first = poslo >> 5;
  int t_last = (poshi - 1) >> 5;  // <= 21

  // compact assignment over active tiles: t = t_first + wid + ti*8
  int tb[3]; int acts[3]; unsigned vb[3]; bool anyact = false;
  const unsigned hvo = (unsigned)(lane >> 5) * (4u * H1_PLANE);
#pragma unroll
  for (int ti = 0; ti < 3; ++ti) {
    int t = t_first + wid + ti * 8;
    bool a = (t <= t_last);
    acts[ti] = __builtin_amdgcn_readfirstlane(a ? 1 : 0);  // wave-uniform -> SGPR
    anyact |= a;
    tb[ti] = t * 32;
    int pos = tb[ti] + (lane & 31);
    if (pos > 675) pos = 675;
    int oy2 = pos / 26, ox2 = pos - oy2 * 26;
    vb[ti] = (unsigned)(oy2 * 30 + ox2) * 8u + hvo;  // inactive: reads don't matter
  }

  f32x16 acc[3];
#pragma unroll
  for (int ti = 0; ti < 3; ++ti)
#pragma unroll
    for (int r = 0; r < 16; ++r) acc[ti][r] = 0.f;

  if (anyact) {
    const uint4* Bp = (const uint4*)(ws + WS_BFRAG);
    uint4 bc0 = Bp[lane * 2 + 0];
    uint4 bc1 = Bp[lane * 2 + 1];
#pragma unroll
    for (int t = 0; t < 25; ++t) {
      uint4 bn0, bn1;
      if (t < 24) {
        bn0 = Bp[(t + 1) * 128 + lane * 2 + 0];
        bn1 = Bp[(t + 1) * 128 + lane * 2 + 1];
      }
      const int dtap = ((t / 5) * 30 + (t % 5)) * 8;
      v8i bop = (v8i){(int)bc0.x, (int)bc0.y, (int)bc0.z, (int)bc0.w,
                      (int)bc1.x, (int)bc1.y, (int)bc1.z, (int)bc1.w};
#pragma unroll
      for (int ti = 0; ti < 3; ++ti) {
        if (!acts[ti]) continue;
        uint2 a0 = *(const uint2*)(smem + vb[ti] + 0 * H1_PLANE + dtap);
        uint2 a1 = *(const uint2*)(smem + vb[ti] + 1 * H1_PLANE + dtap);
        uint2 a2 = *(const uint2*)(smem + vb[ti] + 2 * H1_PLANE + dtap);
        uint2 a3 = *(const uint2*)(smem + vb[ti] + 3 * H1_PLANE + dtap);
        v8i aop = (v8i){(int)a0.x, (int)a0.y, (int)a1.x, (int)a1.y,
                        (int)a2.x, (int)a2.y, (int)a3.x, (int)a3.y};
        acc[ti] = __builtin_amdgcn_mfma_scale_f32_32x32x64_f8f6f4(
            aop, bop, acc[ti], 0, 0, 0, 0x7F7F7F7F, 0, 0x7F7F7F7F);
      }
      bc0 = bn0; bc1 = bn1;
    }
  }
  __syncthreads();  // all h1 reads done; c2 may now overwrite h1's LDS region

  // c2 writes: compact owners write computed tiles; fixed mapping covers the
  // rest with bias only (exact: h1 is zero outside [t_first,t_last] range).
  unsigned short* c2 = (unsigned short*)smem;
#pragma unroll
  for (int ti = 0; ti < 3; ++ti) {
    if (!acts[ti]) continue;
#pragma unroll
    for (int r = 0; r < 16; ++r) {
      int row = (r & 3) + 8 * (r >> 2) + 4 * (lane >> 5);
      int pos = tb[ti] + row;
      if (pos < 676) c2[pos * 32 + oc] = f2bf(acc[ti][r] + c2bb);
    }
  }
  {
    unsigned short cu = f2bf(c2bb);
#pragma unroll
    for (int ti = 0; ti < 3; ++ti) {
      int tf = wid + ti * 8;
      if (tf < 22 && (tf < t_first || tf > t_last)) {
#pragma unroll
        for (int r = 0; r < 16; ++r) {
          int row = (r & 3) + 8 * (r >> 2) + 4 * (lane >> 5);
          int pos = tf * 32 + row;
          if (pos < 676) c2[pos * 32 + oc] = cu;
        }
      }
    }
  }
  __syncthreads();

  // ---- phase 3: pool2 + spatial mean (lanes 0..31 -> consecutive oc) ----
  {
    float* partial = (float*)(smem + SM_PART);
    int moc = lane & 31;
    int mi = wid * 2 + (lane >> 5);  // 0..15
    float ssum = 0.f;
    for (int q = mi; q < 169; q += 16) {
      int py = q / 13, px = q - py * 13;
      int p0 = (py * 2) * 26 + px * 2;
      float v00 = bflo(c2[p0 * 32 + moc]);
      float v01 = bflo(c2[(p0 + 1) * 32 + moc]);
      float v10 = bflo(c2[(p0 + 26) * 32 + moc]);
      float v11 = bflo(c2[(p0 + 27) * 32 + moc]);
      ssum += fmaxf(fmaxf(v00, v01), fmaxf(v10, v11));
    }
    partial[mi * 32 + moc] = ssum;
  }
  __syncthreads();
  if (tid < 32) {
    const float* partial = (const float*)(smem + SM_PART);
    float s = 0.f;
#pragma unroll
    for (int mi = 0; mi < 16; ++mi) s += partial[mi * 32 + tid];
    ((float*)(smem + SM_HM))[tid] = s * (1.0f / 169.0f);
  }
  __syncthreads();

  // ---- phase 4: FC + ReLU (fcw streamed from L2; no register prefetch) ----
  {
    const float* hm = (const float*)(smem + SM_HM);
    float a = fcb[tid];
    const float* wrow = fcw + tid * 32;
#pragma unroll 8
    for (int o2 = 0; o2 < 32; ++o2) a = fmaf(hm[o2], wrow[o2], a);
    out[p * 512 + tid] = fmaxf(a, 0.f);
  }
}

extern "C" void kernel_launch(void* const* d_in, const int* in_sizes, int n_in,
                              void* d_out, int out_size, void* d_ws, size_t ws_size,
                              hipStream_t stream) {
  const float* bboxes = (const float*)d_in[0];
  const float* w1 = (const float*)d_in[1];
  const float* b1 = (const float*)d_in[2];
  const float* w2 = (const float*)d_in[3];
  const float* b2 = (const float*)d_in[4];
  const float* fcw = (const float*)d_in[5];
  const float* fcb = (const float*)d_in[6];
  float* out = (float*)d_out;
  unsigned char* ws = (unsigned char*)d_ws;

  hipLaunchKernelGGL(prep_kernel, dim3(80), dim3(256), 0, stream, w1, b1, w2, out, ws);
  hipLaunchKernelGGL(main_kernel, dim3(NPAIRS), dim3(512), 0, stream, bboxes, b2, fcw, fcb, ws, out);
}

// Round 6
// 70.237 us; speedup vs baseline: 2.2811x; 1.1505x over previous
//
#include <hip/hip_runtime.h>
#include <hip/hip_bf16.h>

// SpatialBranch: 1088 box-pair indicator maps -> conv1(2->64,5x5)+pool2 ->
// conv2(64->32,5x5)+pool2 -> spatial mean -> FC(32->512)+ReLU, plus slicing.
//
// Round 6 changes (phase-1 gather path was the bottleneck):
//  - V window-table stored fp8 (72-B padded rows) and STAGED INTO LDS once per
//    block; phase-1 per-lane gathers become ds_read_b64 (broadcast-friendly)
//    instead of divergent global_load_dwordx4 through L1. Unpack via
//    v_cvt_pk_f32_fp8.
//  - c2 row stride 32 -> 36 shorts (72 B) to spread b16 writes/reads over all
//    32 banks (was concentrated in banks 0..15).
//  - Keeps R5: MX K=64 fp8 MFMA, transposed h1 planes, compact active tiles,
//    bias folding. LDS 74.2 KB -> still 2 blocks/CU.

#define NPAIRS 1088
#define FEAT_SZ (NPAIRS * 512)

typedef float f32x16 __attribute__((ext_vector_type(16)));
typedef int v8i __attribute__((ext_vector_type(8)));
typedef float floatx2 __attribute__((ext_vector_type(2)));

// workspace layout (bytes)
#define WS_V 0            // V fp8 [200 rows][72 B] = 14400 (rows: c*100+sy*10+sx)
#define WS_C2B 14400      // 32 f32 (conv1-bias folded through conv2)
#define WS_BFRAG 14528    // 25 taps x 64 lanes x 32B fp8 = 51200
// total 65728 bytes of ws

// LDS layout (bytes)
#define H1_PLANE 7200     // 900 rows x 8B per 8-channel plane
#define H1_BYTES 57600    // 8 planes; phase>=3: c2 [676][36] bf16 = 48672 aliases
#define SM_V 57600        // V fp8 [200][72] = 14400
#define SM_HM 72000       // h_mean [32] f32
#define SM_PART 72128     // partial [16][32] f32 = 2048
#define SMEM_BYTES 74176

__device__ __forceinline__ unsigned short f2bf(float f) {
  __hip_bfloat16 h = __float2bfloat16(f);
  unsigned short u;
  __builtin_memcpy(&u, &h, 2);
  return u;
}
__device__ __forceinline__ float bflo(unsigned int u) { return __uint_as_float(u << 16); }

__device__ __forceinline__ void fp8x8_to_f32(uint2 u, float* f) {
  floatx2 t;
  t = __builtin_amdgcn_cvt_pk_f32_fp8((int)u.x, false); f[0] = t.x; f[1] = t.y;
  t = __builtin_amdgcn_cvt_pk_f32_fp8((int)u.x, true);  f[2] = t.x; f[3] = t.y;
  t = __builtin_amdgcn_cvt_pk_f32_fp8((int)u.y, false); f[4] = t.x; f[5] = t.y;
  t = __builtin_amdgcn_cvt_pk_f32_fp8((int)u.y, true);  f[6] = t.x; f[7] = t.y;
}

__device__ __forceinline__ void pair_ij(int k, int* pi, int* pj) {
  int i = 0, rem = k;
  while (rem >= 16 - i) { rem -= 16 - i; ++i; }
  *pi = i;
  *pj = i + 1 + rem;
}

// window state for coordinate z vs interval [a,b): 0 empty, 1..4 left-partial
// (k0=s,k1=5), 5 full, 6..9 right-partial (k0=0,k1=s-5). Valid since b-a>=4.
__device__ __forceinline__ int stz(int z, int a, int b) {
  if (z >= a) {
    if (z >= b) return 0;
    if (z <= b - 5) return 5;
    return 5 + (b - z);
  }
  if (z >= a - 4) return a - z;
  return 0;
}

__global__ void prep_kernel(const float* __restrict__ w1, const float* __restrict__ b1,
                            const float* __restrict__ w2, float* __restrict__ out,
                            unsigned char* __restrict__ ws) {
  int tid = blockIdx.x * blockDim.x + threadIdx.x;

  if (tid < 12800) {
    // V[c][sy][sx][o] fp8: conv1 response of window-state (sy,sx) = rect subsum
    int o = tid & 63;
    int q = tid >> 6;
    int sx = q % 10; q /= 10;
    int sy = q % 10;
    int c = q / 10;
    int ky0 = (sy <= 4) ? sy : 0;
    int ky1 = (sy == 0) ? 0 : ((sy <= 5) ? 5 : sy - 5);
    int kx0 = (sx <= 4) ? sx : 0;
    int kx1 = (sx == 0) ? 0 : ((sx <= 5) ? 5 : sx - 5);
    const float* w = w1 + (o * 2 + c) * 25;
    float v = 0.f;
    for (int ky = ky0; ky < ky1; ++ky)
      for (int kx = kx0; kx < kx1; ++kx) v += w[ky * 5 + kx];
    unsigned qv = __builtin_amdgcn_cvt_pk_fp8_f32(v, v, 0, false);
    ((unsigned char*)(ws + WS_V))[(c * 100 + sy * 10 + sx) * 72 + o] = (unsigned char)(qv & 0xFF);
  } else if (tid < 12832) {
    // C2B[oc] = sum_ic b1[ic] * sum_tap w2[oc][ic][tap]
    int oc = tid - 12800;
    float s = 0.f;
    for (int ic = 0; ic < 64; ++ic) {
      const float* wp = w2 + (oc * 64 + ic) * 25;
      float t = 0.f;
      for (int q2 = 0; q2 < 25; ++q2) t += wp[q2];
      s += b1[ic] * t;
    }
    ((float*)(ws + WS_C2B))[oc] = s;
  } else if (tid < 13920) {
    // slicing output (as float values; d_out read back as float32)
    int p = tid - 12832;
    int b = p / 136, k = p % 136, i, j;
    pair_ij(k, &i, &j);
    out[FEAT_SZ + p * 3 + 0] = (float)b;
    out[FEAT_SZ + p * 3 + 1] = (float)i;
    out[FEAT_SZ + p * 3 + 2] = (float)j;
  } else if (tid < 15520) {
    // conv2 B fragments (fp8) for K=64 MX MFMA: one tap per step.
    // lane l: n = l&31 (oc), h = l>>5; k-bytes = w2[oc][ic = h*32 + 0..31][tap]
    int idx = tid - 13920;
    int tap = idx >> 6, lane = idx & 63;
    int n = lane & 31, h = lane >> 5;
    unsigned qd[8];
#pragma unroll
    for (int d = 0; d < 8; ++d) {
      float v0 = w2[(n * 64 + h * 32 + 4 * d + 0) * 25 + tap];
      float v1 = w2[(n * 64 + h * 32 + 4 * d + 1) * 25 + tap];
      float v2 = w2[(n * 64 + h * 32 + 4 * d + 2) * 25 + tap];
      float v3 = w2[(n * 64 + h * 32 + 4 * d + 3) * 25 + tap];
      unsigned q = 0;
      q = __builtin_amdgcn_cvt_pk_fp8_f32(v0, v1, q, false);
      q = __builtin_amdgcn_cvt_pk_fp8_f32(v2, v3, q, true);
      qd[d] = q;
    }
    uint4* Bp = (uint4*)(ws + WS_BFRAG);
    Bp[tap * 128 + lane * 2 + 0] = make_uint4(qd[0], qd[1], qd[2], qd[3]);
    Bp[tap * 128 + lane * 2 + 1] = make_uint4(qd[4], qd[5], qd[6], qd[7]);
  }
}

__global__ __launch_bounds__(512, 4) void main_kernel(
    const float* __restrict__ bboxes, const float* __restrict__ b2,
    const float* __restrict__ fcw, const float* __restrict__ fcb,
    const unsigned char* __restrict__ ws, float* __restrict__ out) {
  __shared__ __align__(16) unsigned char smem[SMEM_BYTES];
  const int tid = threadIdx.x;
  const int lane = tid & 63;
  const int wid = tid >> 6;
  const int p = blockIdx.x;

  // ---- stage V table into LDS (14400 B, coalesced) ----
  {
    const uint4* Vsrc = (const uint4*)(ws + WS_V);
    uint4* Vdst = (uint4*)(smem + SM_V);
    for (int i = tid; i < 900; i += 512) Vdst[i] = Vsrc[i];
  }

  // ---- pair constants (uniform; overlaps the V copy) ----
  int b = p / 136, k = p % 136, bi, bj;
  pair_ij(k, &bi, &bj);
  const float* bbA = bboxes + (b * 17 + bi) * 4;
  const float* bbB = bboxes + (b * 17 + bj) * 4;
  int ax[2], ay[2], bx[2], by[2];
  {
    auto cl = [](float v) { int t = (int)ceilf(v); return t < 0 ? 0 : (t > 64 ? 64 : t); };
    ax[0] = cl(bbA[0]); ay[0] = cl(bbA[1]); bx[0] = cl(bbA[2]); by[0] = cl(bbA[3]);
    ax[1] = cl(bbB[0]); ay[1] = cl(bbB[1]); bx[1] = cl(bbB[2]); by[1] = cl(bbB[3]);
  }
  __syncthreads();  // V staged

  // ---- phase 1: conv1 + pool1 via V lookups (LDS); h1 fp8 planes, no b1 ----
  {
    for (int pos = tid; pos < 900; pos += 512) {
      int py = pos / 30, px = pos - py * 30;
      int oy = py * 2, ox = px * 2;
      int sy[2][2], sx[2][2];
#pragma unroll
      for (int c = 0; c < 2; ++c) {
        sy[c][0] = stz(oy, ay[c], by[c]);
        sy[c][1] = stz(oy + 1, ay[c], by[c]);
        sx[c][0] = stz(ox, ax[c], bx[c]);
        sx[c][1] = stz(ox + 1, ax[c], bx[c]);
      }
      bool e0 = ((sy[0][0] | sy[0][1]) == 0) || ((sx[0][0] | sx[0][1]) == 0);
      bool e1 = ((sy[1][0] | sy[1][1]) == 0) || ((sx[1][0] | sx[1][1]) == 0);
      unsigned hbase = (unsigned)pos * 8u;
      if (e0 && e1) {
#pragma unroll
        for (int g = 0; g < 8; ++g)
          *(uint2*)(smem + hbase + g * H1_PLANE) = make_uint2(0u, 0u);
        continue;
      }

      unsigned r0o[4], r1o[4];
#pragma unroll
      for (int dy = 0; dy < 2; ++dy)
#pragma unroll
        for (int dx = 0; dx < 2; ++dx) {
          r0o[dy * 2 + dx] = SM_V + (unsigned)(sy[0][dy] * 10 + sx[0][dx]) * 72u;
          r1o[dy * 2 + dx] = SM_V + 7200u + (unsigned)(sy[1][dy] * 10 + sx[1][dx]) * 72u;
        }

#pragma unroll
      for (int g = 0; g < 8; ++g) {  // 8 channels per group -> plane g
        float mx[8];
#pragma unroll
        for (int sp = 0; sp < 4; ++sp) {
          uint2 u0 = *(const uint2*)(smem + r0o[sp] + g * 8);
          uint2 u1 = *(const uint2*)(smem + r1o[sp] + g * 8);
          float a[8], c[8];
          fp8x8_to_f32(u0, a);
          fp8x8_to_f32(u1, c);
#pragma unroll
          for (int d = 0; d < 8; ++d) {
            float v = a[d] + c[d];
            mx[d] = (sp == 0) ? v : fmaxf(mx[d], v);
          }
        }
        unsigned q0 = 0, q1 = 0;
        q0 = __builtin_amdgcn_cvt_pk_fp8_f32(mx[0], mx[1], q0, false);
        q0 = __builtin_amdgcn_cvt_pk_fp8_f32(mx[2], mx[3], q0, true);
        q1 = __builtin_amdgcn_cvt_pk_fp8_f32(mx[4], mx[5], q1, false);
        q1 = __builtin_amdgcn_cvt_pk_fp8_f32(mx[6], mx[7], q1, true);
        *(uint2*)(smem + hbase + g * H1_PLANE) = make_uint2(q0, q1);
      }
    }
  }
  __syncthreads();

  // ---- phase 2: conv2 as K=64 MX fp8 MFMA implicit GEMM over ACTIVE tiles ----
  const int oc = lane & 31;
  const float c2bb = ((const float*)(ws + WS_C2B))[oc] + b2[oc];

  // active conv2 output row range (h1 zero outside support; bias folded -> valid skip)
  int s0a = ay[0] - 4 < 0 ? 0 : ay[0] - 4;
  int s0b = ay[1] - 4 < 0 ? 0 : ay[1] - 4;
  int pre0 = s0a < s0b ? s0a : s0b;
  int e0a = by[0] < 60 ? by[0] : 60;
  int e0b = by[1] < 60 ? by[1] : 60;
  int pre1 = e0a > e0b ? e0a : e0b;
  int pr0 = pre0 >> 1, pr1 = (pre1 - 1) >> 1;
  int or0 = pr0 - 4 < 0 ? 0 : pr0 - 4;
  int or1 = pr1 > 25 ? 25 : pr1;
  int poslo = or0 * 26, poshi = (or1 + 1) * 26;
  int t_first = poslo >> 5;
  int t_last = (poshi - 1) >> 5;  // <= 21

  // compact assignment over active tiles: t = t_first + wid + ti*8
  int tb[3]; int acts[3]; unsigned vb[3]; bool anyact = false;
  const unsigned hvo = (unsigned)(lane >> 5) * (4u * H1_PLANE);
#pragma unroll
  for (int ti = 0; ti < 3; ++ti) {
    int t = t_first + wid + ti * 8;
    bool a = (t <= t_last);
    acts[ti] = __builtin_amdgcn_readfirstlane(a ? 1 : 0);  // wave-uniform -> SGPR
    anyact |= a;
    tb[ti] = t * 32;
    int pos = tb[ti] + (lane & 31);
    if (pos > 675) pos = 675;
    int oy2 = pos / 26, ox2 = pos - oy2 * 26;
    vb[ti] = (unsigned)(oy2 * 30 + ox2) * 8u + hvo;  // inactive: reads don't matter
  }

  f32x16 acc[3];
#pragma unroll
  for (int ti = 0; ti < 3; ++ti)
#pragma unroll
    for (int r = 0; r < 16; ++r) acc[ti][r] = 0.f;

  if (anyact) {
    const uint4* Bp = (const uint4*)(ws + WS_BFRAG);
    uint4 bc0 = Bp[lane * 2 + 0];
    uint4 bc1 = Bp[lane * 2 + 1];
#pragma unroll
    for (int t = 0; t < 25; ++t) {
      uint4 bn0, bn1;
      if (t < 24) {
        bn0 = Bp[(t + 1) * 128 + lane * 2 + 0];
        bn1 = Bp[(t + 1) * 128 + lane * 2 + 1];
      }
      const int dtap = ((t / 5) * 30 + (t % 5)) * 8;
      v8i bop = (v8i){(int)bc0.x, (int)bc0.y, (int)bc0.z, (int)bc0.w,
                      (int)bc1.x, (int)bc1.y, (int)bc1.z, (int)bc1.w};
#pragma unroll
      for (int ti = 0; ti < 3; ++ti) {
        if (!acts[ti]) continue;
        uint2 a0 = *(const uint2*)(smem + vb[ti] + 0 * H1_PLANE + dtap);
        uint2 a1 = *(const uint2*)(smem + vb[ti] + 1 * H1_PLANE + dtap);
        uint2 a2 = *(const uint2*)(smem + vb[ti] + 2 * H1_PLANE + dtap);
        uint2 a3 = *(const uint2*)(smem + vb[ti] + 3 * H1_PLANE + dtap);
        v8i aop = (v8i){(int)a0.x, (int)a0.y, (int)a1.x, (int)a1.y,
                        (int)a2.x, (int)a2.y, (int)a3.x, (int)a3.y};
        acc[ti] = __builtin_amdgcn_mfma_scale_f32_32x32x64_f8f6f4(
            aop, bop, acc[ti], 0, 0, 0, 0x7F7F7F7F, 0, 0x7F7F7F7F);
      }
      bc0 = bn0; bc1 = bn1;
    }
  }
  __syncthreads();  // all h1 reads done; c2 may now overwrite h1's LDS region

  // c2 writes (stride 36 shorts = 72 B for bank spread): compact owners write
  // computed tiles; fixed mapping covers the rest with bias only (exact).
  unsigned short* c2 = (unsigned short*)smem;
#pragma unroll
  for (int ti = 0; ti < 3; ++ti) {
    if (!acts[ti]) continue;
#pragma unroll
    for (int r = 0; r < 16; ++r) {
      int row = (r & 3) + 8 * (r >> 2) + 4 * (lane >> 5);
      int pos = tb[ti] + row;
      if (pos < 676) c2[pos * 36 + oc] = f2bf(acc[ti][r] + c2bb);
    }
  }
  {
    unsigned short cu = f2bf(c2bb);
#pragma unroll
    for (int ti = 0; ti < 3; ++ti) {
      int tf = wid + ti * 8;
      if (tf < 22 && (tf < t_first || tf > t_last)) {
#pragma unroll
        for (int r = 0; r < 16; ++r) {
          int row = (r & 3) + 8 * (r >> 2) + 4 * (lane >> 5);
          int pos = tf * 32 + row;
          if (pos < 676) c2[pos * 36 + oc] = cu;
        }
      }
    }
  }
  __syncthreads();

  // ---- phase 3: pool2 + spatial mean (lanes 0..31 -> consecutive oc) ----
  {
    float* partial = (float*)(smem + SM_PART);
    int moc = lane & 31;
    int mi = wid * 2 + (lane >> 5);  // 0..15
    float ssum = 0.f;
    for (int q = mi; q < 169; q += 16) {
      int py = q / 13, px = q - py * 13;
      int p0 = (py * 2) * 26 + px * 2;
      float v00 = bflo(c2[p0 * 36 + moc]);
      float v01 = bflo(c2[(p0 + 1) * 36 + moc]);
      float v10 = bflo(c2[(p0 + 26) * 36 + moc]);
      float v11 = bflo(c2[(p0 + 27) * 36 + moc]);
      ssum += fmaxf(fmaxf(v00, v01), fmaxf(v10, v11));
    }
    partial[mi * 32 + moc] = ssum;
  }
  __syncthreads();
  if (tid < 32) {
    const float* partial = (const float*)(smem + SM_PART);
    float s = 0.f;
#pragma unroll
    for (int mi = 0; mi < 16; ++mi) s += partial[mi * 32 + tid];
    ((float*)(smem + SM_HM))[tid] = s * (1.0f / 169.0f);
  }
  __syncthreads();

  // ---- phase 4: FC + ReLU (fcw streamed from L2; no register prefetch) ----
  {
    const float* hm = (const float*)(smem + SM_HM);
    float a = fcb[tid];
    const float* wrow = fcw + tid * 32;
#pragma unroll 8
    for (int o2 = 0; o2 < 32; ++o2) a = fmaf(hm[o2], wrow[o2], a);
    out[p * 512 + tid] = fmaxf(a, 0.f);
  }
}

extern "C" void kernel_launch(void* const* d_in, const int* in_sizes, int n_in,
                              void* d_out, int out_size, void* d_ws, size_t ws_size,
                              hipStream_t stream) {
  const float* bboxes = (const float*)d_in[0];
  const float* w1 = (const float*)d_in[1];
  const float* b1 = (const float*)d_in[2];
  const float* w2 = (const float*)d_in[3];
  const float* b2 = (const float*)d_in[4];
  const float* fcw = (const float*)d_in[5];
  const float* fcb = (const float*)d_in[6];
  float* out = (float*)d_out;
  unsigned char* ws = (unsigned char*)d_ws;

  hipLaunchKernelGGL(prep_kernel, dim3(80), dim3(256), 0, stream, w1, b1, w2, out, ws);
  hipLaunchKernelGGL(main_kernel, dim3(NPAIRS), dim3(512), 0, stream, bboxes, b2, fcw, fcb, ws, out);
}

// Round 8
// 66.559 us; speedup vs baseline: 2.4072x; 1.0553x over previous
//
#include <hip/hip_runtime.h>
#include <hip/hip_bf16.h>

// SpatialBranch: 1088 box-pair indicator maps -> conv1(2->64,5x5)+pool2 ->
// conv2(64->32,5x5)+pool2 -> spatial mean -> FC(32->512)+ReLU, plus slicing.
//
// Round 8 = Round 7 + correctness fix:
//  - R7 BUG: phase-1 zero-row skip used the SUPPORT range [or0, or1+4], but
//    phase 2 reads TILE-ALIGNED ranges (t_first*32 .. (t_last+1)*32) -> rows
//    outside the support range but inside the tile range were never written
//    (stale LDS) and fed the MFMA. Fix: zr0/zr1 derived from tile-aligned
//    positions: zr0 = (t_first*32)/26, zr1 = min(29, (pos_end-1)/26 + 4).
//  - Keeps R7: 3-deep B prefetch, c2T [32][706] packed bf16 epilogue + paired
//    b32 pool reads, trimmed phase 1, finer prep split, float4 fcw loads.

#define NPAIRS 1088
#define FEAT_SZ (NPAIRS * 512)

typedef float f32x16 __attribute__((ext_vector_type(16)));
typedef int v8i __attribute__((ext_vector_type(8)));
typedef float floatx2 __attribute__((ext_vector_type(2)));

// workspace layout (bytes)
#define WS_V 0            // V fp8 [200 rows][72 B] = 14400 (rows: c*100+sy*10+sx)
#define WS_C2B 14400      // 32 f32 (conv1-bias folded through conv2)
#define WS_BFRAG 14528    // 25 taps x 64 lanes x 32B fp8 = 51200
// total 65728 bytes of ws

// LDS layout (bytes)
#define H1_PLANE 7200     // 900 rows x 8B per 8-channel plane
#define H1_BYTES 57600    // 8 planes; phase>=3: c2T [32][706] bf16 = 45184 aliases
#define SM_V 57600        // V fp8 [200][72] = 14400
#define SM_HM 72000       // h_mean [32] f32
#define SM_PART 72128     // partial [16][32] f32 = 2048
#define SMEM_BYTES 74176

__device__ __forceinline__ unsigned short f2bf(float f) {
  __hip_bfloat16 h = __float2bfloat16(f);
  unsigned short u;
  __builtin_memcpy(&u, &h, 2);
  return u;
}
__device__ __forceinline__ float bflo(unsigned int u) { return __uint_as_float(u << 16); }
__device__ __forceinline__ float bfhi(unsigned int u) { return __uint_as_float(u & 0xffff0000u); }

__device__ __forceinline__ void fp8x8_to_f32(uint2 u, float* f) {
  floatx2 t;
  t = __builtin_amdgcn_cvt_pk_f32_fp8((int)u.x, false); f[0] = t.x; f[1] = t.y;
  t = __builtin_amdgcn_cvt_pk_f32_fp8((int)u.x, true);  f[2] = t.x; f[3] = t.y;
  t = __builtin_amdgcn_cvt_pk_f32_fp8((int)u.y, false); f[4] = t.x; f[5] = t.y;
  t = __builtin_amdgcn_cvt_pk_f32_fp8((int)u.y, true);  f[6] = t.x; f[7] = t.y;
}

__device__ __forceinline__ void pair_ij(int k, int* pi, int* pj) {
  int i = 0, rem = k;
  while (rem >= 16 - i) { rem -= 16 - i; ++i; }
  *pi = i;
  *pj = i + 1 + rem;
}

// window state for coordinate z vs interval [a,b): 0 empty, 1..4 left-partial
// (k0=s,k1=5), 5 full, 6..9 right-partial (k0=0,k1=s-5). Valid since b-a>=4.
__device__ __forceinline__ int stz(int z, int a, int b) {
  if (z >= a) {
    if (z >= b) return 0;
    if (z <= b - 5) return 5;
    return 5 + (b - z);
  }
  if (z >= a - 4) return a - z;
  return 0;
}

__global__ void prep_kernel(const float* __restrict__ w1, const float* __restrict__ b1,
                            const float* __restrict__ w2, float* __restrict__ out,
                            unsigned char* __restrict__ ws) {
  int tid = blockIdx.x * blockDim.x + threadIdx.x;

  if (tid < 12800) {
    // V[c][sy][sx][o] fp8: conv1 response of window-state (sy,sx) = rect subsum
    int o = tid & 63;
    int q = tid >> 6;
    int sx = q % 10; q /= 10;
    int sy = q % 10;
    int c = q / 10;
    int ky0 = (sy <= 4) ? sy : 0;
    int ky1 = (sy == 0) ? 0 : ((sy <= 5) ? 5 : sy - 5);
    int kx0 = (sx <= 4) ? sx : 0;
    int kx1 = (sx == 0) ? 0 : ((sx <= 5) ? 5 : sx - 5);
    const float* w = w1 + (o * 2 + c) * 25;
    float v = 0.f;
    for (int ky = ky0; ky < ky1; ++ky)
      for (int kx = kx0; kx < kx1; ++kx) v += w[ky * 5 + kx];
    unsigned qv = __builtin_amdgcn_cvt_pk_fp8_f32(v, v, 0, false);
    ((unsigned char*)(ws + WS_V))[(c * 100 + sy * 10 + sx) * 72 + o] = (unsigned char)(qv & 0xFF);
  } else if (tid < 12832) {
    // C2B[oc] = sum_ic b1[ic] * sum_tap w2[oc][ic][tap]
    int oc = tid - 12800;
    float s = 0.f;
    for (int ic = 0; ic < 64; ++ic) {
      const float* wp = w2 + (oc * 64 + ic) * 25;
      float t = 0.f;
      for (int q2 = 0; q2 < 25; ++q2) t += wp[q2];
      s += b1[ic] * t;
    }
    ((float*)(ws + WS_C2B))[oc] = s;
  } else if (tid < 13920) {
    // slicing output (as float values; d_out read back as float32)
    int p = tid - 12832;
    int b = p / 136, k = p % 136, i, j;
    pair_ij(k, &i, &j);
    out[FEAT_SZ + p * 3 + 0] = (float)b;
    out[FEAT_SZ + p * 3 + 1] = (float)i;
    out[FEAT_SZ + p * 3 + 2] = (float)j;
  } else if (tid < 26720) {
    // conv2 B fragments (fp8), fine split: one dword per thread.
    // dword index = tap*512 + lane*8 + d ; covers ic = (lane>>5)*32 + 4d + 0..3
    int idx = tid - 13920;          // [0, 12800)
    int d = idx & 7;
    int lane = (idx >> 3) & 63;
    int tap = idx >> 9;
    int n = lane & 31, h = lane >> 5;
    int icb = h * 32 + d * 4;
    float v0 = w2[(n * 64 + icb + 0) * 25 + tap];
    float v1 = w2[(n * 64 + icb + 1) * 25 + tap];
    float v2 = w2[(n * 64 + icb + 2) * 25 + tap];
    float v3 = w2[(n * 64 + icb + 3) * 25 + tap];
    unsigned q = 0;
    q = __builtin_amdgcn_cvt_pk_fp8_f32(v0, v1, q, false);
    q = __builtin_amdgcn_cvt_pk_fp8_f32(v2, v3, q, true);
    ((unsigned*)(ws + WS_BFRAG))[tap * 512 + lane * 8 + d] = q;
  }
}

__global__ __launch_bounds__(512, 4) void main_kernel(
    const float* __restrict__ bboxes, const float* __restrict__ b2,
    const float* __restrict__ fcw, const float* __restrict__ fcb,
    const unsigned char* __restrict__ ws, float* __restrict__ out) {
  __shared__ __align__(16) unsigned char smem[SMEM_BYTES];
  const int tid = threadIdx.x;
  const int lane = tid & 63;
  const int wid = tid >> 6;
  const int p = blockIdx.x;

  // ---- stage V table into LDS (14400 B, coalesced) ----
  {
    const uint4* Vsrc = (const uint4*)(ws + WS_V);
    uint4* Vdst = (uint4*)(smem + SM_V);
    for (int i = tid; i < 900; i += 512) Vdst[i] = Vsrc[i];
  }

  // ---- pair constants (uniform; overlaps the V copy) ----
  int b = p / 136, k = p % 136, bi, bj;
  pair_ij(k, &bi, &bj);
  const float* bbA = bboxes + (b * 17 + bi) * 4;
  const float* bbB = bboxes + (b * 17 + bj) * 4;
  int ax[2], ay[2], bx[2], by[2];
  {
    auto cl = [](float v) { int t = (int)ceilf(v); return t < 0 ? 0 : (t > 64 ? 64 : t); };
    ax[0] = cl(bbA[0]); ay[0] = cl(bbA[1]); bx[0] = cl(bbA[2]); by[0] = cl(bbA[3]);
    ax[1] = cl(bbB[0]); ay[1] = cl(bbB[1]); bx[1] = cl(bbB[2]); by[1] = cl(bbB[3]);
  }

  // active conv2 output row range (h1 zero outside support; bias folded -> valid skip)
  int s0a = ay[0] - 4 < 0 ? 0 : ay[0] - 4;
  int s0b = ay[1] - 4 < 0 ? 0 : ay[1] - 4;
  int pre0 = s0a < s0b ? s0a : s0b;
  int e0a = by[0] < 60 ? by[0] : 60;
  int e0b = by[1] < 60 ? by[1] : 60;
  int pre1 = e0a > e0b ? e0a : e0b;
  int pr0 = pre0 >> 1, pr1 = (pre1 - 1) >> 1;
  int or0 = pr0 - 4 < 0 ? 0 : pr0 - 4;
  int or1 = pr1 > 25 ? 25 : pr1;
  int poslo = or0 * 26, poshi = (or1 + 1) * 26;
  int t_first = poslo >> 5;
  int t_last = (poshi - 1) >> 5;  // <= 21

  // h1 rows phase 2 actually reads -- derived from the TILE-ALIGNED pos range
  // (tiles extend beyond the support range on both sides; R7 bug was using
  // the support range here).
  int pos_end = (t_last + 1) * 32; if (pos_end > 676) pos_end = 676;
  int zr0 = (t_first * 32) / 26;
  int zr1 = (pos_end - 1) / 26 + 4; if (zr1 > 29) zr1 = 29;

  __syncthreads();  // V staged

  // ---- phase 1: conv1 + pool1 via V lookups (LDS); h1 fp8 planes, no b1.
  //      Only rows [zr0, zr1] are ever read -> skip the rest entirely. ----
  {
    for (int pos = tid; pos < 900; pos += 512) {
      int py = pos / 30, px = pos - py * 30;
      if (py < zr0 || py > zr1) continue;  // never read by phase 2
      int oy = py * 2, ox = px * 2;
      int sy[2][2], sx[2][2];
#pragma unroll
      for (int c = 0; c < 2; ++c) {
        sy[c][0] = stz(oy, ay[c], by[c]);
        sy[c][1] = stz(oy + 1, ay[c], by[c]);
        sx[c][0] = stz(ox, ax[c], bx[c]);
        sx[c][1] = stz(ox + 1, ax[c], bx[c]);
      }
      bool e0 = ((sy[0][0] | sy[0][1]) == 0) || ((sx[0][0] | sx[0][1]) == 0);
      bool e1 = ((sy[1][0] | sy[1][1]) == 0) || ((sx[1][0] | sx[1][1]) == 0);
      unsigned hbase = (unsigned)pos * 8u;
      if (e0 && e1) {
#pragma unroll
        for (int g = 0; g < 8; ++g)
          *(uint2*)(smem + hbase + g * H1_PLANE) = make_uint2(0u, 0u);
        continue;
      }

      unsigned r0o[4], r1o[4];
#pragma unroll
      for (int dy = 0; dy < 2; ++dy)
#pragma unroll
        for (int dx = 0; dx < 2; ++dx) {
          r0o[dy * 2 + dx] = SM_V + (unsigned)(sy[0][dy] * 10 + sx[0][dx]) * 72u;
          r1o[dy * 2 + dx] = SM_V + 7200u + (unsigned)(sy[1][dy] * 10 + sx[1][dx]) * 72u;
        }

#pragma unroll
      for (int g = 0; g < 8; ++g) {  // 8 channels per group -> plane g
        float mx[8];
#pragma unroll
        for (int sp = 0; sp < 4; ++sp) {
          uint2 u0 = *(const uint2*)(smem + r0o[sp] + g * 8);
          uint2 u1 = *(const uint2*)(smem + r1o[sp] + g * 8);
          float a[8], c[8];
          fp8x8_to_f32(u0, a);
          fp8x8_to_f32(u1, c);
#pragma unroll
          for (int d = 0; d < 8; ++d) {
            float v = a[d] + c[d];
            mx[d] = (sp == 0) ? v : fmaxf(mx[d], v);
          }
        }
        unsigned q0 = 0, q1 = 0;
        q0 = __builtin_amdgcn_cvt_pk_fp8_f32(mx[0], mx[1], q0, false);
        q0 = __builtin_amdgcn_cvt_pk_fp8_f32(mx[2], mx[3], q0, true);
        q1 = __builtin_amdgcn_cvt_pk_fp8_f32(mx[4], mx[5], q1, false);
        q1 = __builtin_amdgcn_cvt_pk_fp8_f32(mx[6], mx[7], q1, true);
        *(uint2*)(smem + hbase + g * H1_PLANE) = make_uint2(q0, q1);
      }
    }
  }
  __syncthreads();

  // ---- phase 2: conv2 as K=64 MX fp8 MFMA implicit GEMM over ACTIVE tiles ----
  const int oc = lane & 31;
  const float c2bb = ((const float*)(ws + WS_C2B))[oc] + b2[oc];

  // compact assignment over active tiles: t = t_first + wid + ti*8
  int tb[3]; int acts[3]; unsigned vb[3]; bool anyact = false;
  const unsigned hvo = (unsigned)(lane >> 5) * (4u * H1_PLANE);
#pragma unroll
  for (int ti = 0; ti < 3; ++ti) {
    int t = t_first + wid + ti * 8;
    bool a = (t <= t_last);
    acts[ti] = __builtin_amdgcn_readfirstlane(a ? 1 : 0);  // wave-uniform -> SGPR
    anyact |= a;
    tb[ti] = t * 32;
    int pos = tb[ti] + (lane & 31);
    if (pos > 675) pos = 675;
    int oy2 = pos / 26, ox2 = pos - oy2 * 26;
    vb[ti] = (unsigned)(oy2 * 30 + ox2) * 8u + hvo;  // inactive: never read
  }

  f32x16 acc[3];
#pragma unroll
  for (int ti = 0; ti < 3; ++ti)
#pragma unroll
    for (int r = 0; r < 16; ++r) acc[ti][r] = 0.f;

  if (anyact) {
    const uint4* Bp = (const uint4*)(ws + WS_BFRAG);
    uint4 b0[3], b1[3];
#pragma unroll
    for (int t = 0; t < 3; ++t) {
      b0[t] = Bp[t * 128 + lane * 2 + 0];
      b1[t] = Bp[t * 128 + lane * 2 + 1];
    }
#pragma unroll
    for (int t = 0; t < 25; ++t) {
      const int sl = t % 3;  // compile-time under full unroll
      uint4 bc0 = b0[sl], bc1 = b1[sl];
      if (t + 3 < 25) {
        b0[sl] = Bp[(t + 3) * 128 + lane * 2 + 0];
        b1[sl] = Bp[(t + 3) * 128 + lane * 2 + 1];
      }
      const int dtap = ((t / 5) * 30 + (t % 5)) * 8;
      v8i bop = (v8i){(int)bc0.x, (int)bc0.y, (int)bc0.z, (int)bc0.w,
                      (int)bc1.x, (int)bc1.y, (int)bc1.z, (int)bc1.w};
#pragma unroll
      for (int ti = 0; ti < 3; ++ti) {
        if (!acts[ti]) continue;
        uint2 a0 = *(const uint2*)(smem + vb[ti] + 0 * H1_PLANE + dtap);
        uint2 a1 = *(const uint2*)(smem + vb[ti] + 1 * H1_PLANE + dtap);
        uint2 a2 = *(const uint2*)(smem + vb[ti] + 2 * H1_PLANE + dtap);
        uint2 a3 = *(const uint2*)(smem + vb[ti] + 3 * H1_PLANE + dtap);
        v8i aop = (v8i){(int)a0.x, (int)a0.y, (int)a1.x, (int)a1.y,
                        (int)a2.x, (int)a2.y, (int)a3.x, (int)a3.y};
        acc[ti] = __builtin_amdgcn_mfma_scale_f32_32x32x64_f8f6f4(
            aop, bop, acc[ti], 0, 0, 0, 0x7F7F7F7F, 0, 0x7F7F7F7F);
      }
    }
  }
  __syncthreads();  // all h1 reads done; c2T may now overwrite h1's LDS region

  // c2T [32 oc][706 pos] bf16 (aliases h1). Packed b32 writes: dword index =
  // oc*353 + pos/2 (pos even). Rows 676..703 land in the pad -> no bounds checks.
  unsigned* c2w = (unsigned*)smem;
  const int oc353 = oc * 353;
#pragma unroll
  for (int ti = 0; ti < 3; ++ti) {
    if (!acts[ti]) continue;
#pragma unroll
    for (int rp = 0; rp < 8; ++rp) {
      int r = 2 * rp;
      int row = (r & 3) + 8 * (r >> 2) + 4 * (lane >> 5);  // row even; row+1 is r+1
      int pos = tb[ti] + row;
      float lo = acc[ti][r] + c2bb, hi = acc[ti][r + 1] + c2bb;
      unsigned pk;
      asm("v_cvt_pk_bf16_f32 %0, %1, %2" : "=v"(pk) : "v"(lo), "v"(hi));
      c2w[oc353 + (pos >> 1)] = pk;
    }
  }
  {
    unsigned short cu = f2bf(c2bb);
    unsigned cupk = (unsigned)cu | ((unsigned)cu << 16);
#pragma unroll
    for (int ti = 0; ti < 3; ++ti) {
      int tf = wid + ti * 8;
      if (tf < 22 && (tf < t_first || tf > t_last)) {
#pragma unroll
        for (int rp = 0; rp < 8; ++rp) {
          int r = 2 * rp;
          int row = (r & 3) + 8 * (r >> 2) + 4 * (lane >> 5);
          int pos = tf * 32 + row;
          c2w[oc353 + (pos >> 1)] = cupk;
        }
      }
    }
  }
  __syncthreads();

  // ---- phase 3: pool2 + spatial mean (paired b32 reads, conflict-free) ----
  {
    float* partial = (float*)(smem + SM_PART);
    const unsigned* c2r = (const unsigned*)smem;
    int moc = lane & 31;
    int mi = wid * 2 + (lane >> 5);  // 0..15
    int m353 = moc * 353;
    float ssum = 0.f;
    for (int q = mi; q < 169; q += 16) {
      int py = q / 13, px = q - py * 13;
      int halfp = py * 26 + px;  // (py*2*26 + px*2)/2
      unsigned ua = c2r[m353 + halfp];
      unsigned ub = c2r[m353 + halfp + 13];
      float v00 = bflo(ua), v01 = bfhi(ua);
      float v10 = bflo(ub), v11 = bfhi(ub);
      ssum += fmaxf(fmaxf(v00, v01), fmaxf(v10, v11));
    }
    partial[mi * 32 + moc] = ssum;
  }
  __syncthreads();
  if (tid < 32) {
    const float* partial = (const float*)(smem + SM_PART);
    float s = 0.f;
#pragma unroll
    for (int mi = 0; mi < 16; ++mi) s += partial[mi * 32 + tid];
    ((float*)(smem + SM_HM))[tid] = s * (1.0f / 169.0f);
  }
  __syncthreads();

  // ---- phase 4: FC + ReLU (float4 fcw loads, in-phase) ----
  {
    const float* hm = (const float*)(smem + SM_HM);
    const float4* wrow4 = (const float4*)(fcw + tid * 32);
    float a = fcb[tid];
#pragma unroll
    for (int q = 0; q < 8; ++q) {
      float4 w = wrow4[q];
      a = fmaf(hm[4 * q + 0], w.x, a);
      a = fmaf(hm[4 * q + 1], w.y, a);
      a = fmaf(hm[4 * q + 2], w.z, a);
      a = fmaf(hm[4 * q + 3], w.w, a);
    }
    out[p * 512 + tid] = fmaxf(a, 0.f);
  }
}

extern "C" void kernel_launch(void* const* d_in, const int* in_sizes, int n_in,
                              void* d_out, int out_size, void* d_ws, size_t ws_size,
                              hipStream_t stream) {
  const float* bboxes = (const float*)d_in[0];
  const float* w1 = (const float*)d_in[1];
  const float* b1 = (const float*)d_in[2];
  const float* w2 = (const float*)d_in[3];
  const float* b2 = (const float*)d_in[4];
  const float* fcw = (const float*)d_in[5];
  const float* fcb = (const float*)d_in[6];
  float* out = (float*)d_out;
  unsigned char* ws = (unsigned char*)d_ws;

  hipLaunchKernelGGL(prep_kernel, dim3(105), dim3(256), 0, stream, w1, b1, w2, out, ws);
  hipLaunchKernelGGL(main_kernel, dim3(NPAIRS), dim3(512), 0, stream, bboxes, b2, fcw, fcb, ws, out);
}

// Round 9
// 64.707 us; speedup vs baseline: 2.4761x; 1.0286x over previous
//
#include <hip/hip_runtime.h>
#include <hip/hip_bf16.h>

// SpatialBranch: 1088 box-pair indicator maps -> conv1(2->64,5x5)+pool2 ->
// conv2(64->32,5x5)+pool2 -> spatial mean -> FC(32->512)+ReLU, plus slicing.
//
// Round 9 changes (phase-1 VALU + V-gather conflicts; phase-2 LDS instr count):
//  - Tiered phase-1 paths: zero / SINGLE-channel same-state (pure 16B LDS copy,
//    bit-exact: other channel contributes exact 0, requantize is a roundtrip) /
//    single varied (fmax only, no adds) / dual same-state (1 subpos, no fmax) /
//    dual varied (full). Boxes are usually disjoint -> single-channel dominates.
//  - h1 re-laid as 4 plane-PAIRS [900]x16B (stride 14400): phase-2 A-operand =
//    2x ds_read_b128 (16B stride = conflict-free, half the instrs of 4x b64);
//    phase-1 writes 4x uint4 instead of 8x uint2.
//  - Keeps R8: MX K=64 fp8 MFMA, 3-deep B prefetch, c2T packed epilogue/pool,
//    tile-aligned zero-row trim, compact active tiles, bias folding.

#define NPAIRS 1088
#define FEAT_SZ (NPAIRS * 512)

typedef float f32x16 __attribute__((ext_vector_type(16)));
typedef int v8i __attribute__((ext_vector_type(8)));
typedef float floatx2 __attribute__((ext_vector_type(2)));

// workspace layout (bytes)
#define WS_V 0            // V fp8 [200 rows][72 B] = 14400 (rows: c*100+sy*10+sx)
#define WS_C2B 14400      // 32 f32 (conv1-bias folded through conv2)
#define WS_BFRAG 14528    // 25 taps x 64 lanes x 32B fp8 = 51200
// total 65728 bytes of ws

// LDS layout (bytes)
#define H1_PAIR 14400     // one plane-pair: 900 rows x 16B (planes 2pp, 2pp+1)
#define H1_BYTES 57600    // 4 pairs; phase>=3: c2T [32][706] bf16 = 45184 aliases
#define SM_V 57600        // V fp8 [200][72] = 14400
#define SM_HM 72000       // h_mean [32] f32
#define SM_PART 72128     // partial [16][32] f32 = 2048
#define SMEM_BYTES 74176

__device__ __forceinline__ unsigned short f2bf(float f) {
  __hip_bfloat16 h = __float2bfloat16(f);
  unsigned short u;
  __builtin_memcpy(&u, &h, 2);
  return u;
}
__device__ __forceinline__ float bflo(unsigned int u) { return __uint_as_float(u << 16); }
__device__ __forceinline__ float bfhi(unsigned int u) { return __uint_as_float(u & 0xffff0000u); }

__device__ __forceinline__ void fp8x8_to_f32(uint2 u, float* f) {
  floatx2 t;
  t = __builtin_amdgcn_cvt_pk_f32_fp8((int)u.x, false); f[0] = t.x; f[1] = t.y;
  t = __builtin_amdgcn_cvt_pk_f32_fp8((int)u.x, true);  f[2] = t.x; f[3] = t.y;
  t = __builtin_amdgcn_cvt_pk_f32_fp8((int)u.y, false); f[4] = t.x; f[5] = t.y;
  t = __builtin_amdgcn_cvt_pk_f32_fp8((int)u.y, true);  f[6] = t.x; f[7] = t.y;
}

__device__ __forceinline__ unsigned pack_fp8x4(float a, float b, float c, float d) {
  unsigned q = 0;
  q = __builtin_amdgcn_cvt_pk_fp8_f32(a, b, q, false);
  q = __builtin_amdgcn_cvt_pk_fp8_f32(c, d, q, true);
  return q;
}

__device__ __forceinline__ void pair_ij(int k, int* pi, int* pj) {
  int i = 0, rem = k;
  while (rem >= 16 - i) { rem -= 16 - i; ++i; }
  *pi = i;
  *pj = i + 1 + rem;
}

// window state for coordinate z vs interval [a,b): 0 empty, 1..4 left-partial
// (k0=s,k1=5), 5 full, 6..9 right-partial (k0=0,k1=s-5). Valid since b-a>=4.
__device__ __forceinline__ int stz(int z, int a, int b) {
  if (z >= a) {
    if (z >= b) return 0;
    if (z <= b - 5) return 5;
    return 5 + (b - z);
  }
  if (z >= a - 4) return a - z;
  return 0;
}

__global__ void prep_kernel(const float* __restrict__ w1, const float* __restrict__ b1,
                            const float* __restrict__ w2, float* __restrict__ out,
                            unsigned char* __restrict__ ws) {
  int tid = blockIdx.x * blockDim.x + threadIdx.x;

  if (tid < 12800) {
    // V[c][sy][sx][o] fp8: conv1 response of window-state (sy,sx) = rect subsum
    int o = tid & 63;
    int q = tid >> 6;
    int sx = q % 10; q /= 10;
    int sy = q % 10;
    int c = q / 10;
    int ky0 = (sy <= 4) ? sy : 0;
    int ky1 = (sy == 0) ? 0 : ((sy <= 5) ? 5 : sy - 5);
    int kx0 = (sx <= 4) ? sx : 0;
    int kx1 = (sx == 0) ? 0 : ((sx <= 5) ? 5 : sx - 5);
    const float* w = w1 + (o * 2 + c) * 25;
    float v = 0.f;
    for (int ky = ky0; ky < ky1; ++ky)
      for (int kx = kx0; kx < kx1; ++kx) v += w[ky * 5 + kx];
    unsigned qv = __builtin_amdgcn_cvt_pk_fp8_f32(v, v, 0, false);
    ((unsigned char*)(ws + WS_V))[(c * 100 + sy * 10 + sx) * 72 + o] = (unsigned char)(qv & 0xFF);
  } else if (tid < 12832) {
    // C2B[oc] = sum_ic b1[ic] * sum_tap w2[oc][ic][tap]
    int oc = tid - 12800;
    float s = 0.f;
    for (int ic = 0; ic < 64; ++ic) {
      const float* wp = w2 + (oc * 64 + ic) * 25;
      float t = 0.f;
      for (int q2 = 0; q2 < 25; ++q2) t += wp[q2];
      s += b1[ic] * t;
    }
    ((float*)(ws + WS_C2B))[oc] = s;
  } else if (tid < 13920) {
    // slicing output (as float values; d_out read back as float32)
    int p = tid - 12832;
    int b = p / 136, k = p % 136, i, j;
    pair_ij(k, &i, &j);
    out[FEAT_SZ + p * 3 + 0] = (float)b;
    out[FEAT_SZ + p * 3 + 1] = (float)i;
    out[FEAT_SZ + p * 3 + 2] = (float)j;
  } else if (tid < 26720) {
    // conv2 B fragments (fp8), fine split: one dword per thread.
    // dword index = tap*512 + lane*8 + d ; covers ic = (lane>>5)*32 + 4d + 0..3
    int idx = tid - 13920;          // [0, 12800)
    int d = idx & 7;
    int lane = (idx >> 3) & 63;
    int tap = idx >> 9;
    int n = lane & 31, h = lane >> 5;
    int icb = h * 32 + d * 4;
    float v0 = w2[(n * 64 + icb + 0) * 25 + tap];
    float v1 = w2[(n * 64 + icb + 1) * 25 + tap];
    float v2 = w2[(n * 64 + icb + 2) * 25 + tap];
    float v3 = w2[(n * 64 + icb + 3) * 25 + tap];
    ((unsigned*)(ws + WS_BFRAG))[tap * 512 + lane * 8 + d] = pack_fp8x4(v0, v1, v2, v3);
  }
}

__global__ __launch_bounds__(512, 4) void main_kernel(
    const float* __restrict__ bboxes, const float* __restrict__ b2,
    const float* __restrict__ fcw, const float* __restrict__ fcb,
    const unsigned char* __restrict__ ws, float* __restrict__ out) {
  __shared__ __align__(16) unsigned char smem[SMEM_BYTES];
  const int tid = threadIdx.x;
  const int lane = tid & 63;
  const int wid = tid >> 6;
  const int p = blockIdx.x;

  // ---- stage V table into LDS (14400 B, coalesced) ----
  {
    const uint4* Vsrc = (const uint4*)(ws + WS_V);
    uint4* Vdst = (uint4*)(smem + SM_V);
    for (int i = tid; i < 900; i += 512) Vdst[i] = Vsrc[i];
  }

  // ---- pair constants (uniform; overlaps the V copy) ----
  int b = p / 136, k = p % 136, bi, bj;
  pair_ij(k, &bi, &bj);
  const float* bbA = bboxes + (b * 17 + bi) * 4;
  const float* bbB = bboxes + (b * 17 + bj) * 4;
  int ax[2], ay[2], bx[2], by[2];
  {
    auto cl = [](float v) { int t = (int)ceilf(v); return t < 0 ? 0 : (t > 64 ? 64 : t); };
    ax[0] = cl(bbA[0]); ay[0] = cl(bbA[1]); bx[0] = cl(bbA[2]); by[0] = cl(bbA[3]);
    ax[1] = cl(bbB[0]); ay[1] = cl(bbB[1]); bx[1] = cl(bbB[2]); by[1] = cl(bbB[3]);
  }

  // active conv2 output row range (h1 zero outside support; bias folded -> valid skip)
  int s0a = ay[0] - 4 < 0 ? 0 : ay[0] - 4;
  int s0b = ay[1] - 4 < 0 ? 0 : ay[1] - 4;
  int pre0 = s0a < s0b ? s0a : s0b;
  int e0a = by[0] < 60 ? by[0] : 60;
  int e0b = by[1] < 60 ? by[1] : 60;
  int pre1 = e0a > e0b ? e0a : e0b;
  int pr0 = pre0 >> 1, pr1 = (pre1 - 1) >> 1;
  int or0 = pr0 - 4 < 0 ? 0 : pr0 - 4;
  int or1 = pr1 > 25 ? 25 : pr1;
  int poslo = or0 * 26, poshi = (or1 + 1) * 26;
  int t_first = poslo >> 5;
  int t_last = (poshi - 1) >> 5;  // <= 21

  // h1 rows phase 2 actually reads (TILE-ALIGNED pos range; R7 lesson)
  int pos_end = (t_last + 1) * 32; if (pos_end > 676) pos_end = 676;
  int zr0 = (t_first * 32) / 26;
  int zr1 = (pos_end - 1) / 26 + 4; if (zr1 > 29) zr1 = 29;

  __syncthreads();  // V staged

  // ---- phase 1: conv1 + pool1 via V lookups (LDS); h1 fp8 plane-pairs, no b1.
  //      Tiered: zero / single-same (LDS copy) / single / dual-same / dual. ----
  {
    for (int pos = tid; pos < 900; pos += 512) {
      int py = pos / 30, px = pos - py * 30;
      if (py < zr0 || py > zr1) continue;  // never read by phase 2
      int oy = py * 2, ox = px * 2;
      int sy[2][2], sx[2][2];
#pragma unroll
      for (int c = 0; c < 2; ++c) {
        sy[c][0] = stz(oy, ay[c], by[c]);
        sy[c][1] = stz(oy + 1, ay[c], by[c]);
        sx[c][0] = stz(ox, ax[c], bx[c]);
        sx[c][1] = stz(ox + 1, ax[c], bx[c]);
      }
      bool e0 = ((sy[0][0] | sy[0][1]) == 0) || ((sx[0][0] | sx[0][1]) == 0);
      bool e1 = ((sy[1][0] | sy[1][1]) == 0) || ((sx[1][0] | sx[1][1]) == 0);
      unsigned hb = (unsigned)pos * 16u;

      if (e0 && e1) {
#pragma unroll
        for (int pp = 0; pp < 4; ++pp)
          *(uint4*)(smem + pp * H1_PAIR + hb) = make_uint4(0u, 0u, 0u, 0u);
        continue;
      }

      if (e0 || e1) {
        // ---- single active channel ----
        int c = e0 ? 1 : 0;
        unsigned ro[4];
#pragma unroll
        for (int dy = 0; dy < 2; ++dy)
#pragma unroll
          for (int dx = 0; dx < 2; ++dx)
            ro[dy * 2 + dx] =
                SM_V + (unsigned)c * 7200u + (unsigned)(sy[c][dy] * 10 + sx[c][dx]) * 72u;
        bool same = (ro[1] == ro[0]) & (ro[2] == ro[0]) & (ro[3] == ro[0]);
        if (same) {
          // h1 bytes == V row bytes (other channel adds exact 0; requantize is
          // a roundtrip) -> pure LDS->LDS copy.
#pragma unroll
          for (int pp = 0; pp < 4; ++pp) {
            uint2 lo = *(const uint2*)(smem + ro[0] + pp * 16u);
            uint2 hi = *(const uint2*)(smem + ro[0] + pp * 16u + 8u);
            *(uint4*)(smem + pp * H1_PAIR + hb) = make_uint4(lo.x, lo.y, hi.x, hi.y);
          }
        } else {
#pragma unroll
          for (int pp = 0; pp < 4; ++pp) {
            unsigned qv[4];
#pragma unroll
            for (int gg = 0; gg < 2; ++gg) {
              int g = pp * 2 + gg;
              float mx[8];
#pragma unroll
              for (int sp = 0; sp < 4; ++sp) {
                uint2 u = *(const uint2*)(smem + ro[sp] + g * 8u);
                float a[8];
                fp8x8_to_f32(u, a);
#pragma unroll
                for (int d = 0; d < 8; ++d)
                  mx[d] = (sp == 0) ? a[d] : fmaxf(mx[d], a[d]);
              }
              qv[2 * gg + 0] = pack_fp8x4(mx[0], mx[1], mx[2], mx[3]);
              qv[2 * gg + 1] = pack_fp8x4(mx[4], mx[5], mx[6], mx[7]);
            }
            *(uint4*)(smem + pp * H1_PAIR + hb) = make_uint4(qv[0], qv[1], qv[2], qv[3]);
          }
        }
        continue;
      }

      // ---- both channels active ----
      unsigned r0o[4], r1o[4];
#pragma unroll
      for (int dy = 0; dy < 2; ++dy)
#pragma unroll
        for (int dx = 0; dx < 2; ++dx) {
          r0o[dy * 2 + dx] = SM_V + (unsigned)(sy[0][dy] * 10 + sx[0][dx]) * 72u;
          r1o[dy * 2 + dx] = SM_V + 7200u + (unsigned)(sy[1][dy] * 10 + sx[1][dx]) * 72u;
        }
      bool sameA = (r0o[1] == r0o[0]) & (r0o[2] == r0o[0]) & (r0o[3] == r0o[0]);
      bool sameB = (r1o[1] == r1o[0]) & (r1o[2] == r1o[0]) & (r1o[3] == r1o[0]);
      if (sameA && sameB) {
#pragma unroll
        for (int pp = 0; pp < 4; ++pp) {
          unsigned qv[4];
#pragma unroll
          for (int gg = 0; gg < 2; ++gg) {
            int g = pp * 2 + gg;
            uint2 u0 = *(const uint2*)(smem + r0o[0] + g * 8u);
            uint2 u1 = *(const uint2*)(smem + r1o[0] + g * 8u);
            float a[8], c[8];
            fp8x8_to_f32(u0, a);
            fp8x8_to_f32(u1, c);
            qv[2 * gg + 0] = pack_fp8x4(a[0] + c[0], a[1] + c[1], a[2] + c[2], a[3] + c[3]);
            qv[2 * gg + 1] = pack_fp8x4(a[4] + c[4], a[5] + c[5], a[6] + c[6], a[7] + c[7]);
          }
          *(uint4*)(smem + pp * H1_PAIR + hb) = make_uint4(qv[0], qv[1], qv[2], qv[3]);
        }
      } else {
#pragma unroll
        for (int pp = 0; pp < 4; ++pp) {
          unsigned qv[4];
#pragma unroll
          for (int gg = 0; gg < 2; ++gg) {
            int g = pp * 2 + gg;
            float mx[8];
#pragma unroll
            for (int sp = 0; sp < 4; ++sp) {
              uint2 u0 = *(const uint2*)(smem + r0o[sp] + g * 8u);
              uint2 u1 = *(const uint2*)(smem + r1o[sp] + g * 8u);
              float a[8], c[8];
              fp8x8_to_f32(u0, a);
              fp8x8_to_f32(u1, c);
#pragma unroll
              for (int d = 0; d < 8; ++d) {
                float v = a[d] + c[d];
                mx[d] = (sp == 0) ? v : fmaxf(mx[d], v);
              }
            }
            qv[2 * gg + 0] = pack_fp8x4(mx[0], mx[1], mx[2], mx[3]);
            qv[2 * gg + 1] = pack_fp8x4(mx[4], mx[5], mx[6], mx[7]);
          }
          *(uint4*)(smem + pp * H1_PAIR + hb) = make_uint4(qv[0], qv[1], qv[2], qv[3]);
        }
      }
    }
  }
  __syncthreads();

  // ---- phase 2: conv2 as K=64 MX fp8 MFMA implicit GEMM over ACTIVE tiles ----
  const int oc = lane & 31;
  const float c2bb = ((const float*)(ws + WS_C2B))[oc] + b2[oc];

  // compact assignment over active tiles: t = t_first + wid + ti*8
  int tb[3]; int acts[3]; unsigned vb[3]; bool anyact = false;
  const unsigned hvo16 = (unsigned)(lane >> 5) * (2u * H1_PAIR);
#pragma unroll
  for (int ti = 0; ti < 3; ++ti) {
    int t = t_first + wid + ti * 8;
    bool a = (t <= t_last);
    acts[ti] = __builtin_amdgcn_readfirstlane(a ? 1 : 0);  // wave-uniform -> SGPR
    anyact |= a;
    tb[ti] = t * 32;
    int pos = tb[ti] + (lane & 31);
    if (pos > 675) pos = 675;
    int oy2 = pos / 26, ox2 = pos - oy2 * 26;
    vb[ti] = (unsigned)(oy2 * 30 + ox2) * 16u + hvo16;  // inactive: never read
  }

  f32x16 acc[3];
#pragma unroll
  for (int ti = 0; ti < 3; ++ti)
#pragma unroll
    for (int r = 0; r < 16; ++r) acc[ti][r] = 0.f;

  if (anyact) {
    const uint4* Bp = (const uint4*)(ws + WS_BFRAG);
    uint4 b0[3], b1[3];
#pragma unroll
    for (int t = 0; t < 3; ++t) {
      b0[t] = Bp[t * 128 + lane * 2 + 0];
      b1[t] = Bp[t * 128 + lane * 2 + 1];
    }
#pragma unroll
    for (int t = 0; t < 25; ++t) {
      const int sl = t % 3;  // compile-time under full unroll
      uint4 bc0 = b0[sl], bc1 = b1[sl];
      if (t + 3 < 25) {
        b0[sl] = Bp[(t + 3) * 128 + lane * 2 + 0];
        b1[sl] = Bp[(t + 3) * 128 + lane * 2 + 1];
      }
      const unsigned dtap16 = (unsigned)((t / 5) * 30 + (t % 5)) * 16u;
      v8i bop = (v8i){(int)bc0.x, (int)bc0.y, (int)bc0.z, (int)bc0.w,
                      (int)bc1.x, (int)bc1.y, (int)bc1.z, (int)bc1.w};
#pragma unroll
      for (int ti = 0; ti < 3; ++ti) {
        if (!acts[ti]) continue;
        uint4 r0 = *(const uint4*)(smem + vb[ti] + 0u * H1_PAIR + dtap16);
        uint4 r1 = *(const uint4*)(smem + vb[ti] + 1u * H1_PAIR + dtap16);
        v8i aop = (v8i){(int)r0.x, (int)r0.y, (int)r0.z, (int)r0.w,
                        (int)r1.x, (int)r1.y, (int)r1.z, (int)r1.w};
        acc[ti] = __builtin_amdgcn_mfma_scale_f32_32x32x64_f8f6f4(
            aop, bop, acc[ti], 0, 0, 0, 0x7F7F7F7F, 0, 0x7F7F7F7F);
      }
    }
  }
  __syncthreads();  // all h1 reads done; c2T may now overwrite h1's LDS region

  // c2T [32 oc][706 pos] bf16 (aliases h1). Packed b32 writes: dword index =
  // oc*353 + pos/2 (pos even). Rows 676..703 land in the pad -> no bounds checks.
  unsigned* c2w = (unsigned*)smem;
  const int oc353 = oc * 353;
#pragma unroll
  for (int ti = 0; ti < 3; ++ti) {
    if (!acts[ti]) continue;
#pragma unroll
    for (int rp = 0; rp < 8; ++rp) {
      int r = 2 * rp;
      int row = (r & 3) + 8 * (r >> 2) + 4 * (lane >> 5);  // row even; row+1 is r+1
      int pos = tb[ti] + row;
      float lo = acc[ti][r] + c2bb, hi = acc[ti][r + 1] + c2bb;
      unsigned pk;
      asm("v_cvt_pk_bf16_f32 %0, %1, %2" : "=v"(pk) : "v"(lo), "v"(hi));
      c2w[oc353 + (pos >> 1)] = pk;
    }
  }
  {
    unsigned short cu = f2bf(c2bb);
    unsigned cupk = (unsigned)cu | ((unsigned)cu << 16);
#pragma unroll
    for (int ti = 0; ti < 3; ++ti) {
      int tf = wid + ti * 8;
      if (tf < 22 && (tf < t_first || tf > t_last)) {
#pragma unroll
        for (int rp = 0; rp < 8; ++rp) {
          int r = 2 * rp;
          int row = (r & 3) + 8 * (r >> 2) + 4 * (lane >> 5);
          int pos = tf * 32 + row;
          c2w[oc353 + (pos >> 1)] = cupk;
        }
      }
    }
  }
  __syncthreads();

  // ---- phase 3: pool2 + spatial mean (paired b32 reads, conflict-free) ----
  {
    float* partial = (float*)(smem + SM_PART);
    const unsigned* c2r = (const unsigned*)smem;
    int moc = lane & 31;
    int mi = wid * 2 + (lane >> 5);  // 0..15
    int m353 = moc * 353;
    float ssum = 0.f;
    for (int q = mi; q < 169; q += 16) {
      int py = q / 13, px = q - py * 13;
      int halfp = py * 26 + px;  // (py*2*26 + px*2)/2
      unsigned ua = c2r[m353 + halfp];
      unsigned ub = c2r[m353 + halfp + 13];
      float v00 = bflo(ua), v01 = bfhi(ua);
      float v10 = bflo(ub), v11 = bfhi(ub);
      ssum += fmaxf(fmaxf(v00, v01), fmaxf(v10, v11));
    }
    partial[mi * 32 + moc] = ssum;
  }
  __syncthreads();
  if (tid < 32) {
    const float* partial = (const float*)(smem + SM_PART);
    float s = 0.f;
#pragma unroll
    for (int mi = 0; mi < 16; ++mi) s += partial[mi * 32 + tid];
    ((float*)(smem + SM_HM))[tid] = s * (1.0f / 169.0f);
  }
  __syncthreads();

  // ---- phase 4: FC + ReLU (float4 fcw loads, in-phase) ----
  {
    const float* hm = (const float*)(smem + SM_HM);
    const float4* wrow4 = (const float4*)(fcw + tid * 32);
    float a = fcb[tid];
#pragma unroll
    for (int q = 0; q < 8; ++q) {
      float4 w = wrow4[q];
      a = fmaf(hm[4 * q + 0], w.x, a);
      a = fmaf(hm[4 * q + 1], w.y, a);
      a = fmaf(hm[4 * q + 2], w.z, a);
      a = fmaf(hm[4 * q + 3], w.w, a);
    }
    out[p * 512 + tid] = fmaxf(a, 0.f);
  }
}

extern "C" void kernel_launch(void* const* d_in, const int* in_sizes, int n_in,
                              void* d_out, int out_size, void* d_ws, size_t ws_size,
                              hipStream_t stream) {
  const float* bboxes = (const float*)d_in[0];
  const float* w1 = (const float*)d_in[1];
  const float* b1 = (const float*)d_in[2];
  const float* w2 = (const float*)d_in[3];
  const float* b2 = (const float*)d_in[4];
  const float* fcw = (const float*)d_in[5];
  const float* fcb = (const float*)d_in[6];
  float* out = (float*)d_out;
  unsigned char* ws = (unsigned char*)d_ws;

  hipLaunchKernelGGL(prep_kernel, dim3(105), dim3(256), 0, stream, w1, b1, w2, out, ws);
  hipLaunchKernelGGL(main_kernel, dim3(NPAIRS), dim3(512), 0, stream, bboxes, b2, fcw, fcb, ws, out);
}